// Round 5
// baseline (775.994 us; speedup 1.0000x reference)
//
#include <hip/hip_runtime.h>
#include <cstdint>
#include <cstddef>

typedef __bf16 bf16_t;
typedef bf16_t bf16x8 __attribute__((ext_vector_type(8)));
typedef float f32x4 __attribute__((ext_vector_type(4)));

// 8 logical elements -> bf16x8, from an fp32 buffer (external inputs)
static __device__ __forceinline__ bf16x8 ld8_f32(const float* p, size_t i) {
    const f32x4 a = *(const f32x4*)(p + i);
    const f32x4 b = *(const f32x4*)(p + i + 4);
    bf16x8 r;
    r[0] = (bf16_t)a[0]; r[1] = (bf16_t)a[1]; r[2] = (bf16_t)a[2]; r[3] = (bf16_t)a[3];
    r[4] = (bf16_t)b[0]; r[5] = (bf16_t)b[1]; r[6] = (bf16_t)b[2]; r[7] = (bf16_t)b[3];
    return r;
}

// ---------------------------------------------------------------------------
// GEMM: C[M,N] = A[M,K] * Bt[N,K]^T, MFMA 16x16x32 bf16, 128x128 tile, BK=32.
// EXTA/EXTB: operand buffer is fp32 (external input); else bf16 (ws).
// EPI 0: fp32 -> o0[gr*N+gc]                        [out_proj -> d_out]
// EPI 1: gc<2048 -> bf16 o0 (ld 2048) else bf16 o1  [in_proj split xs_pre / z]
// EPI 2: bf16 o0 = softplus(acc + bias_f32[gc])     [dt_proj]
// ---------------------------------------------------------------------------
template<int EXTA, int EXTB, int EPI>
__global__ __launch_bounds__(256)
void gemm128(const void* __restrict__ A, const void* __restrict__ Bt,
             const int M, const int N, const int K,
             void* __restrict__ o0, void* __restrict__ o1,
             const float* __restrict__ bias)
{
    __shared__ __align__(16) bf16_t As[128 * 32];
    __shared__ __align__(16) bf16_t Bs[128 * 32];

    const int tid  = threadIdx.x;
    const int lane = tid & 63;
    const int wave = tid >> 6;
    const int wm = wave & 1, wn = wave >> 1;
    const int m0 = blockIdx.y * 128, n0 = blockIdx.x * 128;
    const int quad = lane >> 4, l16 = lane & 15;

    f32x4 acc[4][4] = {};

    for (int k0 = 0; k0 < K; k0 += 32) {
        __syncthreads();
        {
            const int col = (tid & 3) * 8;
            const int rb  = tid >> 2;
#pragma unroll
            for (int j = 0; j < 2; j++) {
                const int row = rb + j * 64;
                const size_t ib = (size_t)(n0 + row) * K + k0 + col;
                const size_t ia = (size_t)(m0 + row) * K + k0 + col;
                *(bf16x8*)(Bs + row * 32 + col) =
                    EXTB ? ld8_f32((const float*)Bt, ib) : *(const bf16x8*)((const bf16_t*)Bt + ib);
                *(bf16x8*)(As + row * 32 + col) =
                    EXTA ? ld8_f32((const float*)A, ia)  : *(const bf16x8*)((const bf16_t*)A + ia);
            }
        }
        __syncthreads();

        bf16x8 afr[4], bfr[4];
#pragma unroll
        for (int mt = 0; mt < 4; mt++)
            afr[mt] = *(const bf16x8*)(As + (wm * 64 + mt * 16 + l16) * 32 + quad * 8);
#pragma unroll
        for (int nt = 0; nt < 4; nt++)
            bfr[nt] = *(const bf16x8*)(Bs + (wn * 64 + nt * 16 + l16) * 32 + quad * 8);
#pragma unroll
        for (int mt = 0; mt < 4; mt++)
#pragma unroll
            for (int nt = 0; nt < 4; nt++)
                acc[mt][nt] = __builtin_amdgcn_mfma_f32_16x16x32_bf16(
                    afr[mt], bfr[nt], acc[mt][nt], 0, 0, 0);
    }

    // C/D layout (m89-verified): col = lane&15, row = quad*4 + reg
#pragma unroll
    for (int mt = 0; mt < 4; mt++)
#pragma unroll
        for (int nt = 0; nt < 4; nt++)
#pragma unroll
            for (int r = 0; r < 4; r++) {
                const int gr = m0 + wm * 64 + mt * 16 + quad * 4 + r;
                const int gc = n0 + wn * 64 + nt * 16 + l16;
                const float v = acc[mt][nt][r];
                if (EPI == 0) {
                    ((float*)o0)[(size_t)gr * N + gc] = v;
                } else if (EPI == 1) {
                    if (gc < 2048) ((bf16_t*)o0)[(size_t)gr * 2048 + gc] = (bf16_t)v;
                    else           ((bf16_t*)o1)[(size_t)gr * 2048 + (gc - 2048)] = (bf16_t)v;
                } else {
                    const float t  = v + bias[gc];
                    const float sp = (t > 15.f) ? t : log1pf(expf(t));
                    ((bf16_t*)o0)[(size_t)gr * 2048 + gc] = (bf16_t)sp;
                }
            }
}

// ---------------------------------------------------------------------------
// Causal depthwise conv (k=4, fp32 weights/bias) + SiLU. bf16 ws in/out.
// ---------------------------------------------------------------------------
__global__ __launch_bounds__(256)
void conv_silu(const bf16_t* __restrict__ xs_pre, const float* __restrict__ cw,
               const float* __restrict__ cb, bf16_t* __restrict__ xs)
{
    const int idx = blockIdx.x * 256 + threadIdx.x;  // over B*L*2048
    const int d   = idx & 2047;
    const int row = idx >> 11;     // b*L + l
    const int l   = row & 2047;    // L = 2048
    const float w0 = cw[d * 4 + 0], w1 = cw[d * 4 + 1];
    const float w2 = cw[d * 4 + 2], w3 = cw[d * 4 + 3];
    const bf16_t* p = xs_pre + (size_t)row * 2048 + d;
    float acc = cb[d] + w3 * (float)p[0];
    if (l >= 1) acc += w2 * (float)p[-2048];
    if (l >= 2) acc += w1 * (float)p[-4096];
    if (l >= 3) acc += w0 * (float)p[-6144];
    const float s = acc / (1.f + __expf(-acc));
    xs[idx] = (bf16_t)s;
}

// ---------------------------------------------------------------------------
// x_proj: x_dbl[4096,96] = xs[4096,2048](bf16) @ W_xproj[96,2048](fp32)^T.
// dtr (bf16, cols 0..63), Bm (fp32, 64..79), Cm (fp32, 80..95).
// One wave per block, 16 rows.
// ---------------------------------------------------------------------------
__global__ __launch_bounds__(64)
void xproj_kernel(const bf16_t* __restrict__ A, const float* __restrict__ Bt,
                  bf16_t* __restrict__ dtr, float* __restrict__ Bm, float* __restrict__ Cm)
{
    const int lane = threadIdx.x;
    const int m0 = blockIdx.x * 16;
    const int l16 = lane & 15, quad = lane >> 4;
    f32x4 acc[6] = {};

    const bf16_t* ap = A + (size_t)(m0 + l16) * 2048 + quad * 8;
    for (int k0 = 0; k0 < 2048; k0 += 32) {
        const bf16x8 afr = *(const bf16x8*)(ap + k0);
#pragma unroll
        for (int t = 0; t < 6; t++) {
            const bf16x8 bfr = ld8_f32(Bt, (size_t)(t * 16 + l16) * 2048 + k0 + quad * 8);
            acc[t] = __builtin_amdgcn_mfma_f32_16x16x32_bf16(afr, bfr, acc[t], 0, 0, 0);
        }
    }
#pragma unroll
    for (int t = 0; t < 6; t++)
#pragma unroll
        for (int r = 0; r < 4; r++) {
            const int gr = m0 + quad * 4 + r;
            const int gc = t * 16 + l16;
            const float v = acc[t][r];
            if (gc < 64)      dtr[(size_t)gr * 64 + gc] = (bf16_t)v;
            else if (gc < 80) Bm[(size_t)gr * 16 + (gc - 64)] = v;
            else              Cm[(size_t)gr * 16 + (gc - 80)] = v;
        }
}

// ---------------------------------------------------------------------------
// Selective scan + skip + gate. Thread (dl,n): block = 16 d x 16 n.
// Grid = B*128. h (fp32) in register across L. zy: z in, y*silu(z) out
// (in-place, element-wise per block). A_log/Dv are fp32 external.
// ---------------------------------------------------------------------------
__global__ __launch_bounds__(256)
void scan_kernel(const bf16_t* __restrict__ dt, const bf16_t* __restrict__ xs,
                 bf16_t* zy,
                 const float* __restrict__ Bm, const float* __restrict__ Cm,
                 const float* __restrict__ A_log, const float* __restrict__ Dv)
{
    __shared__ float dt_s[64 * 16], x_s[64 * 16], z_s[64 * 16];
    __shared__ float B_s[64 * 16], C_s[64 * 16], y_s[64 * 16];
    const int tid = threadIdx.x;
    const int b  = blockIdx.x >> 7;
    const int d0 = (blockIdx.x & 127) * 16;
    const int n  = tid & 15;
    const int dl = tid >> 4;
    const int d  = d0 + dl;
    const float Adn = -__expf(A_log[(size_t)d * 16 + n]);
    const float Dd  = Dv[d0 + n];   // writer mapping channel = tid&15 = n
    float h = 0.f;
    const size_t brow = (size_t)b * 2048;

    for (int l0 = 0; l0 < 2048; l0 += 64) {
        __syncthreads();
#pragma unroll
        for (int it = 0; it < 4; it++) {
            const int e = tid + it * 256;
            const int i = e >> 4, c = e & 15;
            const size_t gro = (brow + l0 + i) * 2048 + d0 + c;
            dt_s[e] = (float)dt[gro];
            x_s[e]  = (float)xs[gro];
            z_s[e]  = (float)zy[gro];
            const size_t gbc = (brow + l0 + i) * 16 + c;
            B_s[e] = Bm[gbc];
            C_s[e] = Cm[gbc];
        }
        __syncthreads();
#pragma unroll 4
        for (int i = 0; i < 64; i++) {
            const float dtv = dt_s[i * 16 + dl];
            const float dA  = __expf(dtv * Adn);
            const float bx  = dtv * x_s[i * 16 + dl] * B_s[i * 16 + n];
            h = fmaf(h, dA, bx);
            float p = h * C_s[i * 16 + n];
            p += __shfl_xor(p, 1);
            p += __shfl_xor(p, 2);
            p += __shfl_xor(p, 4);
            p += __shfl_xor(p, 8);
            if (n == 0) y_s[i * 16 + dl] = p;
        }
        __syncthreads();
#pragma unroll
        for (int it = 0; it < 4; it++) {
            const int e = tid + it * 256;
            const int i = e >> 4, c = e & 15;
            const float yv = y_s[e] + x_s[e] * Dd;
            const float zv = z_s[e];
            const float g  = zv / (1.f + __expf(-zv));
            zy[(brow + l0 + i) * 2048 + d0 + c] = (bf16_t)(yv * g);
        }
    }
}

// ---------------------------------------------------------------------------
extern "C" void kernel_launch(void* const* d_in, const int* in_sizes, int n_in,
                              void* d_out, int out_size, void* d_ws, size_t ws_size,
                              hipStream_t stream)
{
    const float* x     = (const float*)d_in[0];  // [2,2048,1024]
    const float* W_in  = (const float*)d_in[1];  // [4096,1024]
    const float* convw = (const float*)d_in[2];  // [2048,1,4]
    const float* convb = (const float*)d_in[3];  // [2048]
    const float* W_xp  = (const float*)d_in[4];  // [96,2048]
    const float* W_dt  = (const float*)d_in[5];  // [2048,64]
    const float* b_dt  = (const float*)d_in[6];  // [2048]
    const float* A_log = (const float*)d_in[7];  // [2048,16]
    const float* Dv    = (const float*)d_in[8];  // [2048]
    const float* W_out = (const float*)d_in[9];  // [1024,2048]

    char* ws = (char*)d_ws;
    bf16_t* bufP = (bf16_t*)(ws + 0);           // xs_pre -> later dt   (16.78 MB)
    bf16_t* bufZ = (bf16_t*)(ws + 16777216);    // z -> yg in-place     (16.78 MB)
    bf16_t* bufX = (bf16_t*)(ws + 33554432);    // xs (post conv+silu)  (16.78 MB)
    bf16_t* dtr  = (bf16_t*)(ws + 50331648);    // [4096,64]            (0.52 MB)
    float*  Bm   = (float*)(ws + 50855936);     // [4096,16] fp32
    float*  Cm   = (float*)(ws + 51118080);     // [4096,16] fp32   total ~51.4 MB

    // 1) in_proj: xz = x @ W_in^T -> bufP (xs_pre), bufZ (z)
    gemm128<1, 1, 1><<<dim3(32, 32), dim3(256), 0, stream>>>(
        (const void*)x, (const void*)W_in, 4096, 4096, 1024,
        (void*)bufP, (void*)bufZ, nullptr);

    // 2) conv + bias + silu -> bufX
    conv_silu<<<dim3(32768), dim3(256), 0, stream>>>(bufP, convw, convb, bufX);

    // 3) x_proj -> dtr, Bm, Cm
    xproj_kernel<<<dim3(256), dim3(64), 0, stream>>>(bufX, W_xp, dtr, Bm, Cm);

    // 4) dt_proj + softplus -> bufP (dt)
    gemm128<0, 1, 2><<<dim3(16, 32), dim3(256), 0, stream>>>(
        (const void*)dtr, (const void*)W_dt, 4096, 2048, 64,
        (void*)bufP, nullptr, b_dt);

    // 5) scan + skip + gate -> bufZ in place
    scan_kernel<<<dim3(256), dim3(256), 0, stream>>>(bufP, bufX, bufZ, Bm, Cm, A_log, Dv);

    // 6) out_proj -> d_out (fp32!)
    gemm128<0, 1, 0><<<dim3(8, 32), dim3(256), 0, stream>>>(
        (const void*)bufZ, (const void*)W_out, 4096, 1024, 2048,
        d_out, nullptr, nullptr);
}

// Round 6
// 529.058 us; speedup vs baseline: 1.4667x; 1.4667x over previous
//
#include <hip/hip_runtime.h>
#include <cstdint>
#include <cstddef>

typedef __bf16 bf16_t;
typedef bf16_t bf16x8 __attribute__((ext_vector_type(8)));
typedef float f32x4 __attribute__((ext_vector_type(4)));

// 8 logical elements -> bf16x8, from an fp32 buffer (external inputs)
static __device__ __forceinline__ bf16x8 ld8_f32(const float* p, size_t i) {
    const f32x4 a = *(const f32x4*)(p + i);
    const f32x4 b = *(const f32x4*)(p + i + 4);
    bf16x8 r;
    r[0] = (bf16_t)a[0]; r[1] = (bf16_t)a[1]; r[2] = (bf16_t)a[2]; r[3] = (bf16_t)a[3];
    r[4] = (bf16_t)b[0]; r[5] = (bf16_t)b[1]; r[6] = (bf16_t)b[2]; r[7] = (bf16_t)b[3];
    return r;
}

// ---------------------------------------------------------------------------
// GEMM: C[M,N] = A[M,K] * Bt[N,K]^T, MFMA 16x16x32 bf16, 128x128 tile, BK=32.
// EXTA/EXTB: operand buffer is fp32 (external input); else bf16 (ws).
// EPI 0: fp32 -> o0[gr*N+gc]                        [out_proj -> d_out]
// EPI 1: gc<2048 -> bf16 o0 (ld 2048) else bf16 o1  [in_proj split xs_pre / z]
// EPI 2: bf16 o0 = softplus(acc + bias_f32[gc])     [dt_proj]
// ---------------------------------------------------------------------------
template<int EXTA, int EXTB, int EPI>
__global__ __launch_bounds__(256)
void gemm128(const void* __restrict__ A, const void* __restrict__ Bt,
             const int M, const int N, const int K,
             void* __restrict__ o0, void* __restrict__ o1,
             const float* __restrict__ bias)
{
    __shared__ __align__(16) bf16_t As[128 * 32];
    __shared__ __align__(16) bf16_t Bs[128 * 32];

    const int tid  = threadIdx.x;
    const int lane = tid & 63;
    const int wave = tid >> 6;
    const int wm = wave & 1, wn = wave >> 1;
    const int m0 = blockIdx.y * 128, n0 = blockIdx.x * 128;
    const int quad = lane >> 4, l16 = lane & 15;

    f32x4 acc[4][4] = {};

    for (int k0 = 0; k0 < K; k0 += 32) {
        __syncthreads();
        {
            const int col = (tid & 3) * 8;
            const int rb  = tid >> 2;
#pragma unroll
            for (int j = 0; j < 2; j++) {
                const int row = rb + j * 64;
                const size_t ib = (size_t)(n0 + row) * K + k0 + col;
                const size_t ia = (size_t)(m0 + row) * K + k0 + col;
                *(bf16x8*)(Bs + row * 32 + col) =
                    EXTB ? ld8_f32((const float*)Bt, ib) : *(const bf16x8*)((const bf16_t*)Bt + ib);
                *(bf16x8*)(As + row * 32 + col) =
                    EXTA ? ld8_f32((const float*)A, ia)  : *(const bf16x8*)((const bf16_t*)A + ia);
            }
        }
        __syncthreads();

        bf16x8 afr[4], bfr[4];
#pragma unroll
        for (int mt = 0; mt < 4; mt++)
            afr[mt] = *(const bf16x8*)(As + (wm * 64 + mt * 16 + l16) * 32 + quad * 8);
#pragma unroll
        for (int nt = 0; nt < 4; nt++)
            bfr[nt] = *(const bf16x8*)(Bs + (wn * 64 + nt * 16 + l16) * 32 + quad * 8);
#pragma unroll
        for (int mt = 0; mt < 4; mt++)
#pragma unroll
            for (int nt = 0; nt < 4; nt++)
                acc[mt][nt] = __builtin_amdgcn_mfma_f32_16x16x32_bf16(
                    afr[mt], bfr[nt], acc[mt][nt], 0, 0, 0);
    }

    // C/D layout (m89-verified): col = lane&15, row = quad*4 + reg
#pragma unroll
    for (int mt = 0; mt < 4; mt++)
#pragma unroll
        for (int nt = 0; nt < 4; nt++)
#pragma unroll
            for (int r = 0; r < 4; r++) {
                const int gr = m0 + wm * 64 + mt * 16 + quad * 4 + r;
                const int gc = n0 + wn * 64 + nt * 16 + l16;
                const float v = acc[mt][nt][r];
                if (EPI == 0) {
                    ((float*)o0)[(size_t)gr * N + gc] = v;
                } else if (EPI == 1) {
                    if (gc < 2048) ((bf16_t*)o0)[(size_t)gr * 2048 + gc] = (bf16_t)v;
                    else           ((bf16_t*)o1)[(size_t)gr * 2048 + (gc - 2048)] = (bf16_t)v;
                } else {
                    const float t  = v + bias[gc];
                    const float sp = (t > 15.f) ? t : log1pf(expf(t));
                    ((bf16_t*)o0)[(size_t)gr * 2048 + gc] = (bf16_t)sp;
                }
            }
}

// ---------------------------------------------------------------------------
// Causal depthwise conv (k=4, fp32 weights/bias) + SiLU. bf16 ws in/out.
// ---------------------------------------------------------------------------
__global__ __launch_bounds__(256)
void conv_silu(const bf16_t* __restrict__ xs_pre, const float* __restrict__ cw,
               const float* __restrict__ cb, bf16_t* __restrict__ xs)
{
    const int idx = blockIdx.x * 256 + threadIdx.x;  // over B*L*2048
    const int d   = idx & 2047;
    const int row = idx >> 11;     // b*L + l
    const int l   = row & 2047;    // L = 2048
    const float w0 = cw[d * 4 + 0], w1 = cw[d * 4 + 1];
    const float w2 = cw[d * 4 + 2], w3 = cw[d * 4 + 3];
    const bf16_t* p = xs_pre + (size_t)row * 2048 + d;
    float acc = cb[d] + w3 * (float)p[0];
    if (l >= 1) acc += w2 * (float)p[-2048];
    if (l >= 2) acc += w1 * (float)p[-4096];
    if (l >= 3) acc += w0 * (float)p[-6144];
    const float s = acc / (1.f + __expf(-acc));
    xs[idx] = (bf16_t)s;
}

// ---------------------------------------------------------------------------
// x_proj: x_dbl[4096,96] = xs[4096,2048](bf16) @ W_xproj[96,2048](fp32)^T.
// dtr (bf16, cols 0..63), Bm (fp32, 64..79), Cm (fp32, 80..95).
// One wave per block, 16 rows.
// ---------------------------------------------------------------------------
__global__ __launch_bounds__(64)
void xproj_kernel(const bf16_t* __restrict__ A, const float* __restrict__ Bt,
                  bf16_t* __restrict__ dtr, float* __restrict__ Bm, float* __restrict__ Cm)
{
    const int lane = threadIdx.x;
    const int m0 = blockIdx.x * 16;
    const int l16 = lane & 15, quad = lane >> 4;
    f32x4 acc[6] = {};

    const bf16_t* ap = A + (size_t)(m0 + l16) * 2048 + quad * 8;
    for (int k0 = 0; k0 < 2048; k0 += 32) {
        const bf16x8 afr = *(const bf16x8*)(ap + k0);
#pragma unroll
        for (int t = 0; t < 6; t++) {
            const bf16x8 bfr = ld8_f32(Bt, (size_t)(t * 16 + l16) * 2048 + k0 + quad * 8);
            acc[t] = __builtin_amdgcn_mfma_f32_16x16x32_bf16(afr, bfr, acc[t], 0, 0, 0);
        }
    }
#pragma unroll
    for (int t = 0; t < 6; t++)
#pragma unroll
        for (int r = 0; r < 4; r++) {
            const int gr = m0 + quad * 4 + r;
            const int gc = t * 16 + l16;
            const float v = acc[t][r];
            if (gc < 64)      dtr[(size_t)gr * 64 + gc] = (bf16_t)v;
            else if (gc < 80) Bm[(size_t)gr * 16 + (gc - 64)] = v;
            else              Cm[(size_t)gr * 16 + (gc - 80)] = v;
        }
}

// ---------------------------------------------------------------------------
// Chunk-parallel selective scan (linear recurrence h_t = dA_t h + b_t):
//  S1: per chunk c (len 128), from h=0: local end state H_c and decay A_c=prod dA
//  S2: serial combine over 16 chunks -> seed h0 per chunk (written over Asum)
//  S3: re-run recurrence seeded with h0; y = <h,C>; fuse skip + gate.
// Block = 16 d x 16 n = 256 threads. S1/S3 grid = B*128*16 = 4096 blocks.
// blockIdx encode: bi = (b*128 + dg)*16 + c.
// ---------------------------------------------------------------------------
__global__ __launch_bounds__(256)
void scan_part1(const bf16_t* __restrict__ dt, const bf16_t* __restrict__ xs,
                const float* __restrict__ Bm, const float* __restrict__ A_log,
                float* __restrict__ Asum, float* __restrict__ Hsum)
{
    __shared__ float dt_s[64 * 16], x_s[64 * 16], B_s[64 * 16];
    const int tid = threadIdx.x;
    const int bi  = blockIdx.x;
    const int c   = bi & 15;
    const int dg  = (bi >> 4) & 127;
    const int b   = bi >> 11;
    const int d0  = dg * 16;
    const int n   = tid & 15;
    const int dl  = tid >> 4;
    const float Adn = -__expf(A_log[(size_t)(d0 + dl) * 16 + n]);
    float h = 0.f, ap = 1.f;
    const size_t brow = (size_t)b * 2048 + c * 128;

    for (int l0 = 0; l0 < 128; l0 += 64) {
        __syncthreads();
#pragma unroll
        for (int it = 0; it < 4; it++) {
            const int e = tid + it * 256;
            const int i = e >> 4, cc = e & 15;
            const size_t gro = (brow + l0 + i) * 2048 + d0 + cc;
            dt_s[e] = (float)dt[gro];
            x_s[e]  = (float)xs[gro];
            B_s[e]  = Bm[(brow + l0 + i) * 16 + cc];
        }
        __syncthreads();
#pragma unroll 8
        for (int i = 0; i < 64; i++) {
            const float dtv = dt_s[i * 16 + dl];
            const float dA  = __expf(dtv * Adn);
            const float bx  = dtv * x_s[i * 16 + dl] * B_s[i * 16 + n];
            h  = fmaf(h, dA, bx);
            ap *= dA;
        }
    }
    const size_t si = (size_t)bi * 256 + tid;
    Asum[si] = ap;
    Hsum[si] = h;
}

__global__ __launch_bounds__(256)
void scan_part2(float* __restrict__ Asum, const float* __restrict__ Hsum)
{
    // grid = B*128 blocks; thread (dl,n). Serial over 16 chunks.
    const int tid = threadIdx.x;
    const size_t base = (size_t)blockIdx.x * 16 * 256 + tid;
    float h = 0.f;
#pragma unroll
    for (int c = 0; c < 16; c++) {
        const size_t idx = base + (size_t)c * 256;
        const float a = Asum[idx];
        const float hs = Hsum[idx];
        Asum[idx] = h;            // overwrite with the seed h0 for chunk c
        h = fmaf(a, h, hs);
    }
}

__global__ __launch_bounds__(256)
void scan_part3(const bf16_t* __restrict__ dt, const bf16_t* __restrict__ xs,
                bf16_t* zy,
                const float* __restrict__ Bm, const float* __restrict__ Cm,
                const float* __restrict__ A_log, const float* __restrict__ Dv,
                const float* __restrict__ H0)
{
    __shared__ float dt_s[64 * 16], x_s[64 * 16], z_s[64 * 16];
    __shared__ float B_s[64 * 16], C_s[64 * 16], y_s[64 * 16];
    const int tid = threadIdx.x;
    const int bi  = blockIdx.x;
    const int c   = bi & 15;
    const int dg  = (bi >> 4) & 127;
    const int b   = bi >> 11;
    const int d0  = dg * 16;
    const int n   = tid & 15;
    const int dl  = tid >> 4;
    const float Adn = -__expf(A_log[(size_t)(d0 + dl) * 16 + n]);
    const float Dd  = Dv[d0 + n];   // writer mapping channel = tid&15 = n
    float h = H0[(size_t)bi * 256 + tid];
    const size_t brow = (size_t)b * 2048 + c * 128;

    for (int l0 = 0; l0 < 128; l0 += 64) {
        __syncthreads();
#pragma unroll
        for (int it = 0; it < 4; it++) {
            const int e = tid + it * 256;
            const int i = e >> 4, cc = e & 15;
            const size_t gro = (brow + l0 + i) * 2048 + d0 + cc;
            dt_s[e] = (float)dt[gro];
            x_s[e]  = (float)xs[gro];
            z_s[e]  = (float)zy[gro];
            B_s[e]  = Bm[(brow + l0 + i) * 16 + cc];
            C_s[e]  = Cm[(brow + l0 + i) * 16 + cc];
        }
        __syncthreads();
#pragma unroll 4
        for (int i = 0; i < 64; i++) {
            const float dtv = dt_s[i * 16 + dl];
            const float dA  = __expf(dtv * Adn);
            const float bx  = dtv * x_s[i * 16 + dl] * B_s[i * 16 + n];
            h = fmaf(h, dA, bx);
            float p = h * C_s[i * 16 + n];
            p += __shfl_xor(p, 1);
            p += __shfl_xor(p, 2);
            p += __shfl_xor(p, 4);
            p += __shfl_xor(p, 8);
            if (n == 0) y_s[i * 16 + dl] = p;
        }
        __syncthreads();
#pragma unroll
        for (int it = 0; it < 4; it++) {
            const int e = tid + it * 256;
            const int i = e >> 4, cc = e & 15;
            const float yv = y_s[e] + x_s[e] * Dd;
            const float zv = z_s[e];
            const float g  = zv / (1.f + __expf(-zv));
            zy[(brow + l0 + i) * 2048 + d0 + cc] = (bf16_t)(yv * g);
        }
    }
}

// ---------------------------------------------------------------------------
extern "C" void kernel_launch(void* const* d_in, const int* in_sizes, int n_in,
                              void* d_out, int out_size, void* d_ws, size_t ws_size,
                              hipStream_t stream)
{
    const float* x     = (const float*)d_in[0];  // [2,2048,1024]
    const float* W_in  = (const float*)d_in[1];  // [4096,1024]
    const float* convw = (const float*)d_in[2];  // [2048,1,4]
    const float* convb = (const float*)d_in[3];  // [2048]
    const float* W_xp  = (const float*)d_in[4];  // [96,2048]
    const float* W_dt  = (const float*)d_in[5];  // [2048,64]
    const float* b_dt  = (const float*)d_in[6];  // [2048]
    const float* A_log = (const float*)d_in[7];  // [2048,16]
    const float* Dv    = (const float*)d_in[8];  // [2048]
    const float* W_out = (const float*)d_in[9];  // [1024,2048]

    char* ws = (char*)d_ws;
    bf16_t* bufP = (bf16_t*)(ws + 0);           // xs_pre -> later dt   (16.78 MB)
    bf16_t* bufZ = (bf16_t*)(ws + 16777216);    // z -> yg in-place     (16.78 MB)
    bf16_t* bufX = (bf16_t*)(ws + 33554432);    // xs (post conv+silu)  (16.78 MB)
    bf16_t* dtr  = (bf16_t*)(ws + 50331648);    // [4096,64]            (0.52 MB)
    float*  Bm   = (float*)(ws + 50855936);     // [4096,16] fp32
    float*  Cm   = (float*)(ws + 51118080);     // [4096,16] fp32
    float*  Asum = (float*)(ws + 51380224);     // [4096,256] fp32 -> h0 in place (4 MB)
    float*  Hsum = (float*)(ws + 55574528);     // [4096,256] fp32                (4 MB)
                                                // total ~59.8 MB

    // 1) in_proj: xz = x @ W_in^T -> bufP (xs_pre), bufZ (z)
    gemm128<1, 1, 1><<<dim3(32, 32), dim3(256), 0, stream>>>(
        (const void*)x, (const void*)W_in, 4096, 4096, 1024,
        (void*)bufP, (void*)bufZ, nullptr);

    // 2) conv + bias + silu -> bufX
    conv_silu<<<dim3(32768), dim3(256), 0, stream>>>(bufP, convw, convb, bufX);

    // 3) x_proj -> dtr, Bm, Cm
    xproj_kernel<<<dim3(256), dim3(64), 0, stream>>>(bufX, W_xp, dtr, Bm, Cm);

    // 4) dt_proj + softplus -> bufP (dt)
    gemm128<0, 1, 2><<<dim3(16, 32), dim3(256), 0, stream>>>(
        (const void*)dtr, (const void*)W_dt, 4096, 2048, 64,
        (void*)bufP, nullptr, b_dt);

    // 5) chunk-parallel scan + skip + gate -> bufZ in place
    scan_part1<<<dim3(4096), dim3(256), 0, stream>>>(bufP, bufX, Bm, A_log, Asum, Hsum);
    scan_part2<<<dim3(256),  dim3(256), 0, stream>>>(Asum, Hsum);
    scan_part3<<<dim3(4096), dim3(256), 0, stream>>>(bufP, bufX, bufZ, Bm, Cm, A_log, Dv, Asum);

    // 6) out_proj -> d_out (fp32)
    gemm128<0, 1, 0><<<dim3(8, 32), dim3(256), 0, stream>>>(
        (const void*)bufZ, (const void*)W_out, 4096, 1024, 2048,
        d_out, nullptr, nullptr);
}

// Round 7
// 423.269 us; speedup vs baseline: 1.8333x; 1.2499x over previous
//
#include <hip/hip_runtime.h>
#include <cstdint>
#include <cstddef>

typedef __bf16 bf16_t;
typedef bf16_t bf16x8 __attribute__((ext_vector_type(8)));
typedef float f32x4 __attribute__((ext_vector_type(4)));

// 8 logical elements -> bf16x8, from an fp32 buffer (external inputs)
static __device__ __forceinline__ bf16x8 ld8_f32(const float* p, size_t i) {
    const f32x4 a = *(const f32x4*)(p + i);
    const f32x4 b = *(const f32x4*)(p + i + 4);
    bf16x8 r;
    r[0] = (bf16_t)a[0]; r[1] = (bf16_t)a[1]; r[2] = (bf16_t)a[2]; r[3] = (bf16_t)a[3];
    r[4] = (bf16_t)b[0]; r[5] = (bf16_t)b[1]; r[6] = (bf16_t)b[2]; r[7] = (bf16_t)b[3];
    return r;
}

// ---------------------------------------------------------------------------
// GEMM: C[M,N] = A[M,K] * Bt[N,K]^T, MFMA 16x16x32 bf16, 128x128 tile, BK=32.
// (unchanged from round 6)
// ---------------------------------------------------------------------------
template<int EXTA, int EXTB, int EPI>
__global__ __launch_bounds__(256)
void gemm128(const void* __restrict__ A, const void* __restrict__ Bt,
             const int M, const int N, const int K,
             void* __restrict__ o0, void* __restrict__ o1,
             const float* __restrict__ bias)
{
    __shared__ __align__(16) bf16_t As[128 * 32];
    __shared__ __align__(16) bf16_t Bs[128 * 32];

    const int tid  = threadIdx.x;
    const int lane = tid & 63;
    const int wave = tid >> 6;
    const int wm = wave & 1, wn = wave >> 1;
    const int m0 = blockIdx.y * 128, n0 = blockIdx.x * 128;
    const int quad = lane >> 4, l16 = lane & 15;

    f32x4 acc[4][4] = {};

    for (int k0 = 0; k0 < K; k0 += 32) {
        __syncthreads();
        {
            const int col = (tid & 3) * 8;
            const int rb  = tid >> 2;
#pragma unroll
            for (int j = 0; j < 2; j++) {
                const int row = rb + j * 64;
                const size_t ib = (size_t)(n0 + row) * K + k0 + col;
                const size_t ia = (size_t)(m0 + row) * K + k0 + col;
                *(bf16x8*)(Bs + row * 32 + col) =
                    EXTB ? ld8_f32((const float*)Bt, ib) : *(const bf16x8*)((const bf16_t*)Bt + ib);
                *(bf16x8*)(As + row * 32 + col) =
                    EXTA ? ld8_f32((const float*)A, ia)  : *(const bf16x8*)((const bf16_t*)A + ia);
            }
        }
        __syncthreads();

        bf16x8 afr[4], bfr[4];
#pragma unroll
        for (int mt = 0; mt < 4; mt++)
            afr[mt] = *(const bf16x8*)(As + (wm * 64 + mt * 16 + l16) * 32 + quad * 8);
#pragma unroll
        for (int nt = 0; nt < 4; nt++)
            bfr[nt] = *(const bf16x8*)(Bs + (wn * 64 + nt * 16 + l16) * 32 + quad * 8);
#pragma unroll
        for (int mt = 0; mt < 4; mt++)
#pragma unroll
            for (int nt = 0; nt < 4; nt++)
                acc[mt][nt] = __builtin_amdgcn_mfma_f32_16x16x32_bf16(
                    afr[mt], bfr[nt], acc[mt][nt], 0, 0, 0);
    }

    // C/D layout (m89-verified): col = lane&15, row = quad*4 + reg
#pragma unroll
    for (int mt = 0; mt < 4; mt++)
#pragma unroll
        for (int nt = 0; nt < 4; nt++)
#pragma unroll
            for (int r = 0; r < 4; r++) {
                const int gr = m0 + wm * 64 + mt * 16 + quad * 4 + r;
                const int gc = n0 + wn * 64 + nt * 16 + l16;
                const float v = acc[mt][nt][r];
                if (EPI == 0) {
                    ((float*)o0)[(size_t)gr * N + gc] = v;
                } else if (EPI == 1) {
                    if (gc < 2048) ((bf16_t*)o0)[(size_t)gr * 2048 + gc] = (bf16_t)v;
                    else           ((bf16_t*)o1)[(size_t)gr * 2048 + (gc - 2048)] = (bf16_t)v;
                } else {
                    const float t  = v + bias[gc];
                    const float sp = (t > 15.f) ? t : log1pf(expf(t));
                    ((bf16_t*)o0)[(size_t)gr * 2048 + gc] = (bf16_t)sp;
                }
            }
}

// ---------------------------------------------------------------------------
// Causal depthwise conv (k=4, fp32 weights/bias) + SiLU. (unchanged)
// ---------------------------------------------------------------------------
__global__ __launch_bounds__(256)
void conv_silu(const bf16_t* __restrict__ xs_pre, const float* __restrict__ cw,
               const float* __restrict__ cb, bf16_t* __restrict__ xs)
{
    const int idx = blockIdx.x * 256 + threadIdx.x;  // over B*L*2048
    const int d   = idx & 2047;
    const int row = idx >> 11;     // b*L + l
    const int l   = row & 2047;    // L = 2048
    const float w0 = cw[d * 4 + 0], w1 = cw[d * 4 + 1];
    const float w2 = cw[d * 4 + 2], w3 = cw[d * 4 + 3];
    const bf16_t* p = xs_pre + (size_t)row * 2048 + d;
    float acc = cb[d] + w3 * (float)p[0];
    if (l >= 1) acc += w2 * (float)p[-2048];
    if (l >= 2) acc += w1 * (float)p[-4096];
    if (l >= 3) acc += w0 * (float)p[-6144];
    const float s = acc / (1.f + __expf(-acc));
    xs[idx] = (bf16_t)s;
}

// ---------------------------------------------------------------------------
// x_proj (unchanged)
// ---------------------------------------------------------------------------
__global__ __launch_bounds__(64)
void xproj_kernel(const bf16_t* __restrict__ A, const float* __restrict__ Bt,
                  bf16_t* __restrict__ dtr, float* __restrict__ Bm, float* __restrict__ Cm)
{
    const int lane = threadIdx.x;
    const int m0 = blockIdx.x * 16;
    const int l16 = lane & 15, quad = lane >> 4;
    f32x4 acc[6] = {};

    const bf16_t* ap = A + (size_t)(m0 + l16) * 2048 + quad * 8;
    for (int k0 = 0; k0 < 2048; k0 += 32) {
        const bf16x8 afr = *(const bf16x8*)(ap + k0);
#pragma unroll
        for (int t = 0; t < 6; t++) {
            const bf16x8 bfr = ld8_f32(Bt, (size_t)(t * 16 + l16) * 2048 + k0 + quad * 8);
            acc[t] = __builtin_amdgcn_mfma_f32_16x16x32_bf16(afr, bfr, acc[t], 0, 0, 0);
        }
    }
#pragma unroll
    for (int t = 0; t < 6; t++)
#pragma unroll
        for (int r = 0; r < 4; r++) {
            const int gr = m0 + quad * 4 + r;
            const int gc = t * 16 + l16;
            const float v = acc[t][r];
            if (gc < 64)      dtr[(size_t)gr * 64 + gc] = (bf16_t)v;
            else if (gc < 80) Bm[(size_t)gr * 16 + (gc - 64)] = v;
            else              Cm[(size_t)gr * 16 + (gc - 80)] = v;
        }
}

// ---------------------------------------------------------------------------
// Register-state chunked scan. One THREAD owns one channel d: h[16] in VGPRs.
// No LDS, no shfl. Chunks: NC=64 of T=32 steps. Grid = B*8*64 = 1024 blocks.
//   bi decode: c = bi&63, bb = bi>>6 (= b*8+dblk), d = (bb&7)*256+tid.
// Fast path exploits A[d,n] = -(n+1) (verified at runtime per thread):
//   dA[n] = r^(n+1), r = exp(dt*Adn0); chunk decay = exp(Adn*sum_dt).
// Summaries: sdt fp32 [1024*256], Hsum bf16 [1024*256*16] (seeds in-place).
// ---------------------------------------------------------------------------
static __device__ __forceinline__ bool fast_check(const float* A_log, int d, float& a1) {
    a1 = -__expf(A_log[(size_t)d * 16]);
    bool ok = true;
#pragma unroll
    for (int n = 1; n < 16; n++) {
        const float an = -__expf(A_log[(size_t)d * 16 + n]);
        const float pn = (float)(n + 1) * a1;
        ok = ok && (fabsf(an - pn) <= 1e-3f * fabsf(pn) + 1e-6f);
    }
    return ok;
}

__global__ __launch_bounds__(256)
void scan1(const bf16_t* __restrict__ dt, const bf16_t* __restrict__ xs,
           const float* __restrict__ Bm, const float* __restrict__ A_log,
           float* __restrict__ sdt_o, bf16_t* __restrict__ Hsum)
{
    const int tid = threadIdx.x;
    const int bi  = blockIdx.x;
    const int c   = bi & 63;
    const int bb  = bi >> 6;
    const int b   = bb >> 3;
    const int d   = (bb & 7) * 256 + tid;
    float a1; const bool fast = fast_check(A_log, d, a1);

    float h[16] = {};
    float s = 0.f;
    const size_t rowbase = (size_t)b * 2048 + c * 32;

    if (fast) {
#pragma unroll 4
        for (int t = 0; t < 32; t++) {
            const size_t ro = (rowbase + t) * 2048 + d;
            const float dtv = (float)dt[ro];
            const float xv  = (float)xs[ro];
            s += dtv;
            const float r = __expf(dtv * a1);
            float rp[16]; rp[0] = r;
#pragma unroll
            for (int n = 1; n < 16; n++) rp[n] = rp[n - 1] * r;
            const float bx = dtv * xv;
            const float* bp = Bm + (rowbase + t) * 16;
#pragma unroll
            for (int n = 0; n < 16; n++) h[n] = fmaf(h[n], rp[n], bx * bp[n]);
        }
    } else {
        for (int t = 0; t < 32; t++) {
            const size_t ro = (rowbase + t) * 2048 + d;
            const float dtv = (float)dt[ro];
            const float xv  = (float)xs[ro];
            s += dtv;
            const float bx = dtv * xv;
            const float* bp = Bm + (rowbase + t) * 16;
#pragma unroll
            for (int n = 0; n < 16; n++) {
                const float an = -__expf(A_log[(size_t)d * 16 + n]);
                h[n] = fmaf(h[n], __expf(dtv * an), bx * bp[n]);
            }
        }
    }
    const size_t sb = (size_t)bi * 256 + tid;
    sdt_o[sb] = s;
    bf16x8 h0, h1;
#pragma unroll
    for (int n = 0; n < 8; n++) { h0[n] = (bf16_t)h[n]; h1[n] = (bf16_t)h[n + 8]; }
    *(bf16x8*)(Hsum + sb * 16)     = h0;
    *(bf16x8*)(Hsum + sb * 16 + 8) = h1;
}

__global__ __launch_bounds__(256)
void scan2(const float* __restrict__ sdt, bf16_t* __restrict__ Hsum,
           const float* __restrict__ A_log)
{
    // grid = 16 blocks (bb), 256 threads (d-slot). Serial over 64 chunks.
    const int tid = threadIdx.x;
    const int bb  = blockIdx.x;
    const int d   = (bb & 7) * 256 + tid;
    float a1; const bool fast = fast_check(A_log, d, a1);

    float h[16] = {};
    for (int c = 0; c < 64; c++) {
        const size_t sb = ((size_t)(bb * 64 + c) * 256 + tid);
        const float s = sdt[sb];
        bf16x8 hs0 = *(const bf16x8*)(Hsum + sb * 16);
        bf16x8 hs1 = *(const bf16x8*)(Hsum + sb * 16 + 8);
        // write the seed for chunk c (state BEFORE chunk c)
        bf16x8 o0, o1;
#pragma unroll
        for (int n = 0; n < 8; n++) { o0[n] = (bf16_t)h[n]; o1[n] = (bf16_t)h[n + 8]; }
        *(bf16x8*)(Hsum + sb * 16)     = o0;
        *(bf16x8*)(Hsum + sb * 16 + 8) = o1;
        if (fast) {
            const float r = __expf(s * a1);
            float rp[16]; rp[0] = r;
#pragma unroll
            for (int n = 1; n < 16; n++) rp[n] = rp[n - 1] * r;
#pragma unroll
            for (int n = 0; n < 16; n++) {
                const float hsv = (n < 8) ? (float)hs0[n] : (float)hs1[n - 8];
                h[n] = fmaf(h[n], rp[n], hsv);
            }
        } else {
#pragma unroll
            for (int n = 0; n < 16; n++) {
                const float an = -__expf(A_log[(size_t)d * 16 + n]);
                const float hsv = (n < 8) ? (float)hs0[n] : (float)hs1[n - 8];
                h[n] = fmaf(h[n], __expf(s * an), hsv);
            }
        }
    }
}

__global__ __launch_bounds__(256)
void scan3(const bf16_t* __restrict__ dt, const bf16_t* __restrict__ xs,
           bf16_t* __restrict__ zy,
           const float* __restrict__ Bm, const float* __restrict__ Cm,
           const float* __restrict__ A_log, const float* __restrict__ Dv,
           const bf16_t* __restrict__ Hseed)
{
    const int tid = threadIdx.x;
    const int bi  = blockIdx.x;
    const int c   = bi & 63;
    const int bb  = bi >> 6;
    const int b   = bb >> 3;
    const int d   = (bb & 7) * 256 + tid;
    float a1; const bool fast = fast_check(A_log, d, a1);
    const float Dd = Dv[d];

    const size_t sb = (size_t)bi * 256 + tid;
    const bf16x8 hs0 = *(const bf16x8*)(Hseed + sb * 16);
    const bf16x8 hs1 = *(const bf16x8*)(Hseed + sb * 16 + 8);
    float h[16];
#pragma unroll
    for (int n = 0; n < 8; n++) { h[n] = (float)hs0[n]; h[n + 8] = (float)hs1[n]; }

    const size_t rowbase = (size_t)b * 2048 + c * 32;

    if (fast) {
#pragma unroll 2
        for (int t = 0; t < 32; t++) {
            const size_t ro = (rowbase + t) * 2048 + d;
            const float dtv = (float)dt[ro];
            const float xv  = (float)xs[ro];
            const float zv  = (float)zy[ro];
            const float r = __expf(dtv * a1);
            float rp[16]; rp[0] = r;
#pragma unroll
            for (int n = 1; n < 16; n++) rp[n] = rp[n - 1] * r;
            const float bx = dtv * xv;
            const float* bp = Bm + (rowbase + t) * 16;
            const float* cp = Cm + (rowbase + t) * 16;
            float y0 = 0.f, y1 = 0.f;
#pragma unroll
            for (int n = 0; n < 16; n += 2) {
                h[n]     = fmaf(h[n],     rp[n],     bx * bp[n]);
                h[n + 1] = fmaf(h[n + 1], rp[n + 1], bx * bp[n + 1]);
                y0 = fmaf(h[n],     cp[n],     y0);
                y1 = fmaf(h[n + 1], cp[n + 1], y1);
            }
            const float yv = (y0 + y1) + xv * Dd;
            const float g  = zv / (1.f + __expf(-zv));
            zy[ro] = (bf16_t)(yv * g);
        }
    } else {
        for (int t = 0; t < 32; t++) {
            const size_t ro = (rowbase + t) * 2048 + d;
            const float dtv = (float)dt[ro];
            const float xv  = (float)xs[ro];
            const float zv  = (float)zy[ro];
            const float bx = dtv * xv;
            const float* bp = Bm + (rowbase + t) * 16;
            const float* cp = Cm + (rowbase + t) * 16;
            float y = 0.f;
#pragma unroll
            for (int n = 0; n < 16; n++) {
                const float an = -__expf(A_log[(size_t)d * 16 + n]);
                h[n] = fmaf(h[n], __expf(dtv * an), bx * bp[n]);
                y = fmaf(h[n], cp[n], y);
            }
            const float yv = y + xv * Dd;
            const float g  = zv / (1.f + __expf(-zv));
            zy[ro] = (bf16_t)(yv * g);
        }
    }
}

// ---------------------------------------------------------------------------
extern "C" void kernel_launch(void* const* d_in, const int* in_sizes, int n_in,
                              void* d_out, int out_size, void* d_ws, size_t ws_size,
                              hipStream_t stream)
{
    const float* x     = (const float*)d_in[0];  // [2,2048,1024]
    const float* W_in  = (const float*)d_in[1];  // [4096,1024]
    const float* convw = (const float*)d_in[2];  // [2048,1,4]
    const float* convb = (const float*)d_in[3];  // [2048]
    const float* W_xp  = (const float*)d_in[4];  // [96,2048]
    const float* W_dt  = (const float*)d_in[5];  // [2048,64]
    const float* b_dt  = (const float*)d_in[6];  // [2048]
    const float* A_log = (const float*)d_in[7];  // [2048,16]
    const float* Dv    = (const float*)d_in[8];  // [2048]
    const float* W_out = (const float*)d_in[9];  // [1024,2048]

    char* ws = (char*)d_ws;
    bf16_t* bufP = (bf16_t*)(ws + 0);           // xs_pre -> later dt   (16.78 MB)
    bf16_t* bufZ = (bf16_t*)(ws + 16777216);    // z -> yg in-place     (16.78 MB)
    bf16_t* bufX = (bf16_t*)(ws + 33554432);    // xs (post conv+silu)  (16.78 MB)
    bf16_t* dtr  = (bf16_t*)(ws + 50331648);    // [4096,64]            (0.52 MB)
    float*  Bm   = (float*)(ws + 50855936);     // [4096,16] fp32
    float*  Cm   = (float*)(ws + 51118080);     // [4096,16] fp32
    float*  sdt  = (float*)(ws + 51380224);     // [1024*256] fp32      (1.05 MB)
    bf16_t* Hsum = (bf16_t*)(ws + 52428800);    // [1024*256*16] bf16   (8.39 MB)
                                                // total ~60.8 MB

    // 1) in_proj: xz = x @ W_in^T -> bufP (xs_pre), bufZ (z)
    gemm128<1, 1, 1><<<dim3(32, 32), dim3(256), 0, stream>>>(
        (const void*)x, (const void*)W_in, 4096, 4096, 1024,
        (void*)bufP, (void*)bufZ, nullptr);

    // 2) conv + bias + silu -> bufX
    conv_silu<<<dim3(32768), dim3(256), 0, stream>>>(bufP, convw, convb, bufX);

    // 3) x_proj -> dtr, Bm, Cm
    xproj_kernel<<<dim3(256), dim3(64), 0, stream>>>(bufX, W_xp, dtr, Bm, Cm);

    // 4) dt_proj + softplus -> bufP (dt)
    gemm128<0, 1, 2><<<dim3(16, 32), dim3(256), 0, stream>>>(
        (const void*)dtr, (const void*)W_dt, 4096, 2048, 64,
        (void*)bufP, nullptr, b_dt);

    // 5) register-state chunked scan + skip + gate -> bufZ in place
    scan1<<<dim3(1024), dim3(256), 0, stream>>>(bufP, bufX, Bm, A_log, sdt, Hsum);
    scan2<<<dim3(16),   dim3(256), 0, stream>>>(sdt, Hsum, A_log);
    scan3<<<dim3(1024), dim3(256), 0, stream>>>(bufP, bufX, bufZ, Bm, Cm, A_log, Dv, Hsum);

    // 6) out_proj -> d_out (fp32)
    gemm128<0, 1, 0><<<dim3(8, 32), dim3(256), 0, stream>>>(
        (const void*)bufZ, (const void*)W_out, 4096, 1024, 2048,
        d_out, nullptr, nullptr);
}

// Round 8
// 414.394 us; speedup vs baseline: 1.8726x; 1.0214x over previous
//
#include <hip/hip_runtime.h>
#include <cstdint>
#include <cstddef>

typedef __bf16 bf16_t;
typedef bf16_t bf16x4 __attribute__((ext_vector_type(4)));
typedef bf16_t bf16x8 __attribute__((ext_vector_type(8)));
typedef float f32x4 __attribute__((ext_vector_type(4)));

// async global->LDS, 16B per lane; LDS dest = wave-uniform base + lane*16
static __device__ __forceinline__ void glds16(const void* g, void* l) {
    __builtin_amdgcn_global_load_lds((const __attribute__((address_space(1))) void*)g,
                                     (__attribute__((address_space(3))) void*)l,
                                     16, 0, 0);
}

// ---------------------------------------------------------------------------
// One-shot fp32 -> bf16 cast of the five GEMM operands. 1024 elts / block.
// ---------------------------------------------------------------------------
__global__ __launch_bounds__(256)
void cast5(const float* __restrict__ s0, bf16_t* __restrict__ d0, int n0,
           const float* __restrict__ s1, bf16_t* __restrict__ d1, int n1,
           const float* __restrict__ s2, bf16_t* __restrict__ d2, int n2,
           const float* __restrict__ s3, bf16_t* __restrict__ d3, int n3,
           const float* __restrict__ s4, bf16_t* __restrict__ d4)
{
    int bb = blockIdx.x;
    const float* s; bf16_t* d;
    if (bb < n0)              { s = s0; d = d0; }
    else if ((bb -= n0) < n1) { s = s1; d = d1; }
    else if ((bb -= n1) < n2) { s = s2; d = d2; }
    else if ((bb -= n2) < n3) { s = s3; d = d3; }
    else                      { bb -= n3; s = s4; d = d4; }
    const size_t base = (size_t)bb * 1024 + threadIdx.x * 4;
    const f32x4 v = *(const f32x4*)(s + base);
    bf16x4 o;
    o[0] = (bf16_t)v[0]; o[1] = (bf16_t)v[1]; o[2] = (bf16_t)v[2]; o[3] = (bf16_t)v[3];
    *(bf16x4*)(d + base) = o;
}

// ---------------------------------------------------------------------------
// GEMM: C[M,N] = A[M,K](bf16) * Bt[N,K](bf16)^T, MFMA 16x16x32, 128x128 tile,
// BK=32, glds16 async staging (m97 structure).
// EPI 0: fp32 -> o0[gr*N+gc]                        [out_proj -> d_out]
// EPI 1: gc<2048 -> bf16 o0 (ld 2048) else bf16 o1  [in_proj split xs_pre / z]
// EPI 2: bf16 o0 = softplus(acc + bias_f32[gc])     [dt_proj]
// ---------------------------------------------------------------------------
template<int EPI>
__global__ __launch_bounds__(256)
void gemm_bt(const bf16_t* __restrict__ A, const bf16_t* __restrict__ Bt,
             const int M, const int N, const int K,
             void* __restrict__ o0, void* __restrict__ o1,
             const float* __restrict__ bias)
{
    __shared__ __align__(16) bf16_t As[128 * 32];
    __shared__ __align__(16) bf16_t Bs[128 * 32];

    const int tid  = threadIdx.x;
    const int lane = tid & 63;
    const int wave = tid >> 6;
    const int wm = wave & 1, wn = wave >> 1;
    const int m0 = blockIdx.y * 128, n0 = blockIdx.x * 128;
    const int quad = lane >> 4, l16 = lane & 15;

    f32x4 acc[4][4] = {};

    for (int k0 = 0; k0 < K; k0 += 32) {
        __syncthreads();
#pragma unroll
        for (int j = 0; j < 2; j++) {
            const int u  = wave * 1024 + j * 512;   // wave-uniform LDS elem base
            const int ue = u + lane * 8;            // per-lane element index
            const int row = ue >> 5, col = ue & 31;
            glds16(A  + (size_t)(m0 + row) * K + k0 + col, As + u);
            glds16(Bt + (size_t)(n0 + row) * K + k0 + col, Bs + u);
        }
        __syncthreads();   // compiler drains vmcnt(0) before s_barrier

        bf16x8 afr[4], bfr[4];
#pragma unroll
        for (int mt = 0; mt < 4; mt++)
            afr[mt] = *(const bf16x8*)(As + (wm * 64 + mt * 16 + l16) * 32 + quad * 8);
#pragma unroll
        for (int nt = 0; nt < 4; nt++)
            bfr[nt] = *(const bf16x8*)(Bs + (wn * 64 + nt * 16 + l16) * 32 + quad * 8);
#pragma unroll
        for (int mt = 0; mt < 4; mt++)
#pragma unroll
            for (int nt = 0; nt < 4; nt++)
                acc[mt][nt] = __builtin_amdgcn_mfma_f32_16x16x32_bf16(
                    afr[mt], bfr[nt], acc[mt][nt], 0, 0, 0);
    }

    // C/D layout (m89-verified): col = lane&15, row = quad*4 + reg
#pragma unroll
    for (int mt = 0; mt < 4; mt++)
#pragma unroll
        for (int nt = 0; nt < 4; nt++)
#pragma unroll
            for (int r = 0; r < 4; r++) {
                const int gr = m0 + wm * 64 + mt * 16 + quad * 4 + r;
                const int gc = n0 + wn * 64 + nt * 16 + l16;
                const float v = acc[mt][nt][r];
                if (EPI == 0) {
                    ((float*)o0)[(size_t)gr * N + gc] = v;
                } else if (EPI == 1) {
                    if (gc < 2048) ((bf16_t*)o0)[(size_t)gr * 2048 + gc] = (bf16_t)v;
                    else           ((bf16_t*)o1)[(size_t)gr * 2048 + (gc - 2048)] = (bf16_t)v;
                } else {
                    const float t  = v + bias[gc];
                    const float sp = (t > 15.f) ? t : log1pf(expf(t));
                    ((bf16_t*)o0)[(size_t)gr * 2048 + gc] = (bf16_t)sp;
                }
            }
}

// ---------------------------------------------------------------------------
// Causal depthwise conv (k=4, fp32 weights/bias) + SiLU. (unchanged)
// ---------------------------------------------------------------------------
__global__ __launch_bounds__(256)
void conv_silu(const bf16_t* __restrict__ xs_pre, const float* __restrict__ cw,
               const float* __restrict__ cb, bf16_t* __restrict__ xs)
{
    const int idx = blockIdx.x * 256 + threadIdx.x;  // over B*L*2048
    const int d   = idx & 2047;
    const int row = idx >> 11;     // b*L + l
    const int l   = row & 2047;    // L = 2048
    const float w0 = cw[d * 4 + 0], w1 = cw[d * 4 + 1];
    const float w2 = cw[d * 4 + 2], w3 = cw[d * 4 + 3];
    const bf16_t* p = xs_pre + (size_t)row * 2048 + d;
    float acc = cb[d] + w3 * (float)p[0];
    if (l >= 1) acc += w2 * (float)p[-2048];
    if (l >= 2) acc += w1 * (float)p[-4096];
    if (l >= 3) acc += w0 * (float)p[-6144];
    const float s = acc / (1.f + __expf(-acc));
    xs[idx] = (bf16_t)s;
}

// ---------------------------------------------------------------------------
// x_proj: x_dbl[4096,96] = xs[4096,2048](bf16) @ W_xp_b[96,2048](bf16)^T.
// ---------------------------------------------------------------------------
__global__ __launch_bounds__(64)
void xproj_kernel(const bf16_t* __restrict__ A, const bf16_t* __restrict__ Bt,
                  bf16_t* __restrict__ dtr, float* __restrict__ Bm, float* __restrict__ Cm)
{
    const int lane = threadIdx.x;
    const int m0 = blockIdx.x * 16;
    const int l16 = lane & 15, quad = lane >> 4;
    f32x4 acc[6] = {};

    const bf16_t* ap = A + (size_t)(m0 + l16) * 2048 + quad * 8;
    for (int k0 = 0; k0 < 2048; k0 += 32) {
        const bf16x8 afr = *(const bf16x8*)(ap + k0);
#pragma unroll
        for (int t = 0; t < 6; t++) {
            const bf16x8 bfr = *(const bf16x8*)(Bt + (size_t)(t * 16 + l16) * 2048 + k0 + quad * 8);
            acc[t] = __builtin_amdgcn_mfma_f32_16x16x32_bf16(afr, bfr, acc[t], 0, 0, 0);
        }
    }
#pragma unroll
    for (int t = 0; t < 6; t++)
#pragma unroll
        for (int r = 0; r < 4; r++) {
            const int gr = m0 + quad * 4 + r;
            const int gc = t * 16 + l16;
            const float v = acc[t][r];
            if (gc < 64)      dtr[(size_t)gr * 64 + gc] = (bf16_t)v;
            else if (gc < 80) Bm[(size_t)gr * 16 + (gc - 64)] = v;
            else              Cm[(size_t)gr * 16 + (gc - 80)] = v;
        }
}

// ---------------------------------------------------------------------------
// Register-state chunked scan (unchanged from round 7).
// ---------------------------------------------------------------------------
static __device__ __forceinline__ bool fast_check(const float* A_log, int d, float& a1) {
    a1 = -__expf(A_log[(size_t)d * 16]);
    bool ok = true;
#pragma unroll
    for (int n = 1; n < 16; n++) {
        const float an = -__expf(A_log[(size_t)d * 16 + n]);
        const float pn = (float)(n + 1) * a1;
        ok = ok && (fabsf(an - pn) <= 1e-3f * fabsf(pn) + 1e-6f);
    }
    return ok;
}

__global__ __launch_bounds__(256)
void scan1(const bf16_t* __restrict__ dt, const bf16_t* __restrict__ xs,
           const float* __restrict__ Bm, const float* __restrict__ A_log,
           float* __restrict__ sdt_o, bf16_t* __restrict__ Hsum)
{
    const int tid = threadIdx.x;
    const int bi  = blockIdx.x;
    const int c   = bi & 63;
    const int bb  = bi >> 6;
    const int b   = bb >> 3;
    const int d   = (bb & 7) * 256 + tid;
    float a1; const bool fast = fast_check(A_log, d, a1);

    float h[16] = {};
    float s = 0.f;
    const size_t rowbase = (size_t)b * 2048 + c * 32;

    if (fast) {
#pragma unroll 4
        for (int t = 0; t < 32; t++) {
            const size_t ro = (rowbase + t) * 2048 + d;
            const float dtv = (float)dt[ro];
            const float xv  = (float)xs[ro];
            s += dtv;
            const float r = __expf(dtv * a1);
            float rp[16]; rp[0] = r;
#pragma unroll
            for (int n = 1; n < 16; n++) rp[n] = rp[n - 1] * r;
            const float bx = dtv * xv;
            const float* bp = Bm + (rowbase + t) * 16;
#pragma unroll
            for (int n = 0; n < 16; n++) h[n] = fmaf(h[n], rp[n], bx * bp[n]);
        }
    } else {
        for (int t = 0; t < 32; t++) {
            const size_t ro = (rowbase + t) * 2048 + d;
            const float dtv = (float)dt[ro];
            const float xv  = (float)xs[ro];
            s += dtv;
            const float bx = dtv * xv;
            const float* bp = Bm + (rowbase + t) * 16;
#pragma unroll
            for (int n = 0; n < 16; n++) {
                const float an = -__expf(A_log[(size_t)d * 16 + n]);
                h[n] = fmaf(h[n], __expf(dtv * an), bx * bp[n]);
            }
        }
    }
    const size_t sb = (size_t)bi * 256 + tid;
    sdt_o[sb] = s;
    bf16x8 h0, h1;
#pragma unroll
    for (int n = 0; n < 8; n++) { h0[n] = (bf16_t)h[n]; h1[n] = (bf16_t)h[n + 8]; }
    *(bf16x8*)(Hsum + sb * 16)     = h0;
    *(bf16x8*)(Hsum + sb * 16 + 8) = h1;
}

__global__ __launch_bounds__(256)
void scan2(const float* __restrict__ sdt, bf16_t* __restrict__ Hsum,
           const float* __restrict__ A_log)
{
    const int tid = threadIdx.x;
    const int bb  = blockIdx.x;
    const int d   = (bb & 7) * 256 + tid;
    float a1; const bool fast = fast_check(A_log, d, a1);

    float h[16] = {};
    for (int c = 0; c < 64; c++) {
        const size_t sb = ((size_t)(bb * 64 + c) * 256 + tid);
        const float s = sdt[sb];
        bf16x8 hs0 = *(const bf16x8*)(Hsum + sb * 16);
        bf16x8 hs1 = *(const bf16x8*)(Hsum + sb * 16 + 8);
        bf16x8 o0, o1;
#pragma unroll
        for (int n = 0; n < 8; n++) { o0[n] = (bf16_t)h[n]; o1[n] = (bf16_t)h[n + 8]; }
        *(bf16x8*)(Hsum + sb * 16)     = o0;
        *(bf16x8*)(Hsum + sb * 16 + 8) = o1;
        if (fast) {
            const float r = __expf(s * a1);
            float rp[16]; rp[0] = r;
#pragma unroll
            for (int n = 1; n < 16; n++) rp[n] = rp[n - 1] * r;
#pragma unroll
            for (int n = 0; n < 16; n++) {
                const float hsv = (n < 8) ? (float)hs0[n] : (float)hs1[n - 8];
                h[n] = fmaf(h[n], rp[n], hsv);
            }
        } else {
#pragma unroll
            for (int n = 0; n < 16; n++) {
                const float an = -__expf(A_log[(size_t)d * 16 + n]);
                const float hsv = (n < 8) ? (float)hs0[n] : (float)hs1[n - 8];
                h[n] = fmaf(h[n], __expf(s * an), hsv);
            }
        }
    }
}

__global__ __launch_bounds__(256)
void scan3(const bf16_t* __restrict__ dt, const bf16_t* __restrict__ xs,
           bf16_t* __restrict__ zy,
           const float* __restrict__ Bm, const float* __restrict__ Cm,
           const float* __restrict__ A_log, const float* __restrict__ Dv,
           const bf16_t* __restrict__ Hseed)
{
    const int tid = threadIdx.x;
    const int bi  = blockIdx.x;
    const int c   = bi & 63;
    const int bb  = bi >> 6;
    const int b   = bb >> 3;
    const int d   = (bb & 7) * 256 + tid;
    float a1; const bool fast = fast_check(A_log, d, a1);
    const float Dd = Dv[d];

    const size_t sb = (size_t)bi * 256 + tid;
    const bf16x8 hs0 = *(const bf16x8*)(Hseed + sb * 16);
    const bf16x8 hs1 = *(const bf16x8*)(Hseed + sb * 16 + 8);
    float h[16];
#pragma unroll
    for (int n = 0; n < 8; n++) { h[n] = (float)hs0[n]; h[n + 8] = (float)hs1[n]; }

    const size_t rowbase = (size_t)b * 2048 + c * 32;

    if (fast) {
#pragma unroll 2
        for (int t = 0; t < 32; t++) {
            const size_t ro = (rowbase + t) * 2048 + d;
            const float dtv = (float)dt[ro];
            const float xv  = (float)xs[ro];
            const float zv  = (float)zy[ro];
            const float r = __expf(dtv * a1);
            float rp[16]; rp[0] = r;
#pragma unroll
            for (int n = 1; n < 16; n++) rp[n] = rp[n - 1] * r;
            const float bx = dtv * xv;
            const float* bp = Bm + (rowbase + t) * 16;
            const float* cp = Cm + (rowbase + t) * 16;
            float y0 = 0.f, y1 = 0.f;
#pragma unroll
            for (int n = 0; n < 16; n += 2) {
                h[n]     = fmaf(h[n],     rp[n],     bx * bp[n]);
                h[n + 1] = fmaf(h[n + 1], rp[n + 1], bx * bp[n + 1]);
                y0 = fmaf(h[n],     cp[n],     y0);
                y1 = fmaf(h[n + 1], cp[n + 1], y1);
            }
            const float yv = (y0 + y1) + xv * Dd;
            const float g  = zv / (1.f + __expf(-zv));
            zy[ro] = (bf16_t)(yv * g);
        }
    } else {
        for (int t = 0; t < 32; t++) {
            const size_t ro = (rowbase + t) * 2048 + d;
            const float dtv = (float)dt[ro];
            const float xv  = (float)xs[ro];
            const float zv  = (float)zy[ro];
            const float bx = dtv * xv;
            const float* bp = Bm + (rowbase + t) * 16;
            const float* cp = Cm + (rowbase + t) * 16;
            float y = 0.f;
#pragma unroll
            for (int n = 0; n < 16; n++) {
                const float an = -__expf(A_log[(size_t)d * 16 + n]);
                h[n] = fmaf(h[n], __expf(dtv * an), bx * bp[n]);
                y = fmaf(h[n], cp[n], y);
            }
            const float yv = y + xv * Dd;
            const float g  = zv / (1.f + __expf(-zv));
            zy[ro] = (bf16_t)(yv * g);
        }
    }
}

// ---------------------------------------------------------------------------
extern "C" void kernel_launch(void* const* d_in, const int* in_sizes, int n_in,
                              void* d_out, int out_size, void* d_ws, size_t ws_size,
                              hipStream_t stream)
{
    const float* x     = (const float*)d_in[0];  // [2,2048,1024]
    const float* W_in  = (const float*)d_in[1];  // [4096,1024]
    const float* convw = (const float*)d_in[2];  // [2048,1,4]
    const float* convb = (const float*)d_in[3];  // [2048]
    const float* W_xp  = (const float*)d_in[4];  // [96,2048]
    const float* W_dt  = (const float*)d_in[5];  // [2048,64]
    const float* b_dt  = (const float*)d_in[6];  // [2048]
    const float* A_log = (const float*)d_in[7];  // [2048,16]
    const float* Dv    = (const float*)d_in[8];  // [2048]
    const float* W_out = (const float*)d_in[9];  // [1024,2048]

    char* ws = (char*)d_ws;
    bf16_t* bufP   = (bf16_t*)(ws + 0);          // xs_pre -> later dt       (16.78 MB)
    bf16_t* bufZ   = (bf16_t*)(ws + 16777216);   // z -> yg in-place         (16.78 MB)
    bf16_t* bufX   = (bf16_t*)(ws + 33554432);   // xs (conv out), stage>=2  (16.78 MB)
    bf16_t* W_in_b = (bf16_t*)(ws + 33554432);   // ALIAS: dead before bufX written
    bf16_t* dtr    = (bf16_t*)(ws + 50331648);   // [4096,64]
    float*  Bm     = (float*)(ws + 50855936);    // [4096,16]
    float*  Cm     = (float*)(ws + 51118080);    // [4096,16]
    float*  sdt    = (float*)(ws + 51380224);    // [1024*256]               (1.05 MB)
    bf16_t* Hsum   = (bf16_t*)(ws + 52428800);   // [1024*256*16], stage 5   (8.39 MB)
    bf16_t* x_b    = (bf16_t*)(ws + 52428800);   // ALIAS: dead before Hsum written
    bf16_t* W_out_b= (bf16_t*)(ws + 60817408);   // [1024,2048]              (4.19 MB)
    bf16_t* W_xp_b = (bf16_t*)(ws + 65011712);   // [96,2048]                (0.39 MB)
    bf16_t* W_dt_b = (bf16_t*)(ws + 65404928);   // [2048,64]                (0.26 MB)
                                                 // total ~65.7 MB

    // 0) cast all GEMM operands fp32 -> bf16 (one fused kernel)
    cast5<<<dim3(4096 + 4096 + 2048 + 192 + 128), dim3(256), 0, stream>>>(
        x, x_b, 4096, W_in, W_in_b, 4096, W_out, W_out_b, 2048,
        W_xp, W_xp_b, 192, W_dt, W_dt_b);

    // 1) in_proj: xz = x @ W_in^T -> bufP (xs_pre), bufZ (z)
    gemm_bt<1><<<dim3(32, 32), dim3(256), 0, stream>>>(
        x_b, W_in_b, 4096, 4096, 1024, (void*)bufP, (void*)bufZ, nullptr);

    // 2) conv + bias + silu -> bufX
    conv_silu<<<dim3(32768), dim3(256), 0, stream>>>(bufP, convw, convb, bufX);

    // 3) x_proj -> dtr, Bm, Cm
    xproj_kernel<<<dim3(256), dim3(64), 0, stream>>>(bufX, W_xp_b, dtr, Bm, Cm);

    // 4) dt_proj + softplus -> bufP (dt)
    gemm_bt<2><<<dim3(16, 32), dim3(256), 0, stream>>>(
        dtr, W_dt_b, 4096, 2048, 64, (void*)bufP, nullptr, b_dt);

    // 5) register-state chunked scan + skip + gate -> bufZ in place
    scan1<<<dim3(1024), dim3(256), 0, stream>>>(bufP, bufX, Bm, A_log, sdt, Hsum);
    scan2<<<dim3(16),   dim3(256), 0, stream>>>(sdt, Hsum, A_log);
    scan3<<<dim3(1024), dim3(256), 0, stream>>>(bufP, bufX, bufZ, Bm, Cm, A_log, Dv, Hsum);

    // 6) out_proj -> d_out (fp32)
    gemm_bt<0><<<dim3(8, 32), dim3(256), 0, stream>>>(
        bufZ, W_out_b, 4096, 1024, 2048, d_out, nullptr, nullptr);
}

// Round 9
// 338.847 us; speedup vs baseline: 2.2901x; 1.2230x over previous
//
#include <hip/hip_runtime.h>
#include <cstdint>
#include <cstddef>

typedef __bf16 bf16_t;
typedef bf16_t bf16x4 __attribute__((ext_vector_type(4)));
typedef bf16_t bf16x8 __attribute__((ext_vector_type(8)));
typedef float f32x4 __attribute__((ext_vector_type(4)));

// async global->LDS, 16B per lane; LDS dest = wave-uniform base + lane*16
static __device__ __forceinline__ void glds16(const void* g, void* l) {
    __builtin_amdgcn_global_load_lds((const __attribute__((address_space(1))) void*)g,
                                     (__attribute__((address_space(3))) void*)l,
                                     16, 0, 0);
}

// ---------------------------------------------------------------------------
// One-shot fp32 -> bf16 cast of the five GEMM operands. 1024 elts / block.
// ---------------------------------------------------------------------------
__global__ __launch_bounds__(256)
void cast5(const float* __restrict__ s0, bf16_t* __restrict__ d0, int n0,
           const float* __restrict__ s1, bf16_t* __restrict__ d1, int n1,
           const float* __restrict__ s2, bf16_t* __restrict__ d2, int n2,
           const float* __restrict__ s3, bf16_t* __restrict__ d3, int n3,
           const float* __restrict__ s4, bf16_t* __restrict__ d4)
{
    int bb = blockIdx.x;
    const float* s; bf16_t* d;
    if (bb < n0)              { s = s0; d = d0; }
    else if ((bb -= n0) < n1) { s = s1; d = d1; }
    else if ((bb -= n1) < n2) { s = s2; d = d2; }
    else if ((bb -= n2) < n3) { s = s3; d = d3; }
    else                      { bb -= n3; s = s4; d = d4; }
    const size_t base = (size_t)bb * 1024 + threadIdx.x * 4;
    const f32x4 v = *(const f32x4*)(s + base);
    bf16x4 o;
    o[0] = (bf16_t)v[0]; o[1] = (bf16_t)v[1]; o[2] = (bf16_t)v[2]; o[3] = (bf16_t)v[3];
    *(bf16x4*)(d + base) = o;
}

// ---------------------------------------------------------------------------
// GEMM: C[M,N] = A[M,K](bf16) * Bt[N,K](bf16)^T, MFMA 16x16x32, 128x128 tile,
// BK=32, glds16 async staging (m97 structure). SPLITK: blockIdx.z picks the
// K-chunk; EPI 3 stores fp32 partials (one buffer per z).
// EPI 0: fp32 -> o0[gr*N+gc]
// EPI 1: gc<2048 -> bf16 o0 (ld 2048) else bf16 o1  [in_proj split xs_pre / z]
// EPI 2: bf16 o0 = softplus(acc + bias_f32[gc])     [dt_proj]
// EPI 3: fp32 partial -> pz[gr*N+gc]                [out_proj split-K]
// ---------------------------------------------------------------------------
template<int EPI, int SPLITK>
__global__ __launch_bounds__(256)
void gemm_bt(const bf16_t* __restrict__ A, const bf16_t* __restrict__ Bt,
             const int M, const int N, const int K,
             void* __restrict__ o0, void* __restrict__ o1,
             const float* __restrict__ bias,
             float* __restrict__ p0, float* __restrict__ p1,
             float* __restrict__ p2, float* __restrict__ p3)
{
    __shared__ __align__(16) bf16_t As[128 * 32];
    __shared__ __align__(16) bf16_t Bs[128 * 32];

    const int tid  = threadIdx.x;
    const int lane = tid & 63;
    const int wave = tid >> 6;
    const int wm = wave & 1, wn = wave >> 1;
    const int m0 = blockIdx.y * 128, n0 = blockIdx.x * 128;
    const int quad = lane >> 4, l16 = lane & 15;
    const int z   = (SPLITK > 1) ? blockIdx.z : 0;
    const int KC  = K / SPLITK;
    const int kb  = z * KC;

    f32x4 acc[4][4] = {};

    for (int k0 = kb; k0 < kb + KC; k0 += 32) {
        __syncthreads();
#pragma unroll
        for (int j = 0; j < 2; j++) {
            const int u  = wave * 1024 + j * 512;   // wave-uniform LDS elem base
            const int ue = u + lane * 8;            // per-lane element index
            const int row = ue >> 5, col = ue & 31;
            glds16(A  + (size_t)(m0 + row) * K + k0 + col, As + u);
            glds16(Bt + (size_t)(n0 + row) * K + k0 + col, Bs + u);
        }
        __syncthreads();

        bf16x8 afr[4], bfr[4];
#pragma unroll
        for (int mt = 0; mt < 4; mt++)
            afr[mt] = *(const bf16x8*)(As + (wm * 64 + mt * 16 + l16) * 32 + quad * 8);
#pragma unroll
        for (int nt = 0; nt < 4; nt++)
            bfr[nt] = *(const bf16x8*)(Bs + (wn * 64 + nt * 16 + l16) * 32 + quad * 8);
#pragma unroll
        for (int mt = 0; mt < 4; mt++)
#pragma unroll
            for (int nt = 0; nt < 4; nt++)
                acc[mt][nt] = __builtin_amdgcn_mfma_f32_16x16x32_bf16(
                    afr[mt], bfr[nt], acc[mt][nt], 0, 0, 0);
    }

    float* pz = (z == 0) ? p0 : (z == 1) ? p1 : (z == 2) ? p2 : p3;

    // C/D layout (m89-verified): col = lane&15, row = quad*4 + reg
#pragma unroll
    for (int mt = 0; mt < 4; mt++)
#pragma unroll
        for (int nt = 0; nt < 4; nt++)
#pragma unroll
            for (int r = 0; r < 4; r++) {
                const int gr = m0 + wm * 64 + mt * 16 + quad * 4 + r;
                const int gc = n0 + wn * 64 + nt * 16 + l16;
                const float v = acc[mt][nt][r];
                if (EPI == 0) {
                    ((float*)o0)[(size_t)gr * N + gc] = v;
                } else if (EPI == 1) {
                    if (gc < 2048) ((bf16_t*)o0)[(size_t)gr * 2048 + gc] = (bf16_t)v;
                    else           ((bf16_t*)o1)[(size_t)gr * 2048 + (gc - 2048)] = (bf16_t)v;
                } else if (EPI == 2) {
                    const float t  = v + bias[gc];
                    const float sp = (t > 15.f) ? t : __logf(1.f + __expf(t));
                    ((bf16_t*)o0)[(size_t)gr * 2048 + gc] = (bf16_t)sp;
                } else {
                    pz[(size_t)gr * N + gc] = v;
                }
            }
}

// ---------------------------------------------------------------------------
// Split-K reduce: d_out[i] = sum_z partial_z[i]  (fp32, f32x4 vectorized)
// ---------------------------------------------------------------------------
__global__ __launch_bounds__(256)
void reduce_k(float* __restrict__ out, const float* __restrict__ p0,
              const float* __restrict__ p1, const float* __restrict__ p2,
              const float* __restrict__ p3, const int nsplit)
{
    const size_t i = ((size_t)blockIdx.x * 256 + threadIdx.x) * 4;
    f32x4 v = *(const f32x4*)(p0 + i);
    v += *(const f32x4*)(p1 + i);
    if (nsplit == 4) {
        v += *(const f32x4*)(p2 + i);
        v += *(const f32x4*)(p3 + i);
    }
    *(f32x4*)(out + i) = v;
}

// ---------------------------------------------------------------------------
// Causal depthwise conv (k=4, fp32 weights/bias) + SiLU. (unchanged)
// ---------------------------------------------------------------------------
__global__ __launch_bounds__(256)
void conv_silu(const bf16_t* __restrict__ xs_pre, const float* __restrict__ cw,
               const float* __restrict__ cb, bf16_t* __restrict__ xs)
{
    const int idx = blockIdx.x * 256 + threadIdx.x;  // over B*L*2048
    const int d   = idx & 2047;
    const int row = idx >> 11;     // b*L + l
    const int l   = row & 2047;    // L = 2048
    const float w0 = cw[d * 4 + 0], w1 = cw[d * 4 + 1];
    const float w2 = cw[d * 4 + 2], w3 = cw[d * 4 + 3];
    const bf16_t* p = xs_pre + (size_t)row * 2048 + d;
    float acc = cb[d] + w3 * (float)p[0];
    if (l >= 1) acc += w2 * (float)p[-2048];
    if (l >= 2) acc += w1 * (float)p[-4096];
    if (l >= 3) acc += w0 * (float)p[-6144];
    const float s = acc / (1.f + __expf(-acc));
    xs[idx] = (bf16_t)s;
}

// ---------------------------------------------------------------------------
// x_proj: x_dbl[4096,96] = xs[4096,2048](bf16) @ W_xp_b[96,2048](bf16)^T.
// ---------------------------------------------------------------------------
__global__ __launch_bounds__(64)
void xproj_kernel(const bf16_t* __restrict__ A, const bf16_t* __restrict__ Bt,
                  bf16_t* __restrict__ dtr, float* __restrict__ Bm, float* __restrict__ Cm)
{
    const int lane = threadIdx.x;
    const int m0 = blockIdx.x * 16;
    const int l16 = lane & 15, quad = lane >> 4;
    f32x4 acc[6] = {};

    const bf16_t* ap = A + (size_t)(m0 + l16) * 2048 + quad * 8;
    for (int k0 = 0; k0 < 2048; k0 += 32) {
        const bf16x8 afr = *(const bf16x8*)(ap + k0);
#pragma unroll
        for (int t = 0; t < 6; t++) {
            const bf16x8 bfr = *(const bf16x8*)(Bt + (size_t)(t * 16 + l16) * 2048 + k0 + quad * 8);
            acc[t] = __builtin_amdgcn_mfma_f32_16x16x32_bf16(afr, bfr, acc[t], 0, 0, 0);
        }
    }
#pragma unroll
    for (int t = 0; t < 6; t++)
#pragma unroll
        for (int r = 0; r < 4; r++) {
            const int gr = m0 + quad * 4 + r;
            const int gc = t * 16 + l16;
            const float v = acc[t][r];
            if (gc < 64)      dtr[(size_t)gr * 64 + gc] = (bf16_t)v;
            else if (gc < 80) Bm[(size_t)gr * 16 + (gc - 64)] = v;
            else              Cm[(size_t)gr * 16 + (gc - 80)] = v;
        }
}

// ---------------------------------------------------------------------------
// Register-state chunked scan (unchanged from round 7).
// ---------------------------------------------------------------------------
static __device__ __forceinline__ bool fast_check(const float* A_log, int d, float& a1) {
    a1 = -__expf(A_log[(size_t)d * 16]);
    bool ok = true;
#pragma unroll
    for (int n = 1; n < 16; n++) {
        const float an = -__expf(A_log[(size_t)d * 16 + n]);
        const float pn = (float)(n + 1) * a1;
        ok = ok && (fabsf(an - pn) <= 1e-3f * fabsf(pn) + 1e-6f);
    }
    return ok;
}

__global__ __launch_bounds__(256)
void scan1(const bf16_t* __restrict__ dt, const bf16_t* __restrict__ xs,
           const float* __restrict__ Bm, const float* __restrict__ A_log,
           float* __restrict__ sdt_o, bf16_t* __restrict__ Hsum)
{
    const int tid = threadIdx.x;
    const int bi  = blockIdx.x;
    const int c   = bi & 63;
    const int bb  = bi >> 6;
    const int b   = bb >> 3;
    const int d   = (bb & 7) * 256 + tid;
    float a1; const bool fast = fast_check(A_log, d, a1);

    float h[16] = {};
    float s = 0.f;
    const size_t rowbase = (size_t)b * 2048 + c * 32;

    if (fast) {
#pragma unroll 4
        for (int t = 0; t < 32; t++) {
            const size_t ro = (rowbase + t) * 2048 + d;
            const float dtv = (float)dt[ro];
            const float xv  = (float)xs[ro];
            s += dtv;
            const float r = __expf(dtv * a1);
            float rp[16]; rp[0] = r;
#pragma unroll
            for (int n = 1; n < 16; n++) rp[n] = rp[n - 1] * r;
            const float bx = dtv * xv;
            const float* bp = Bm + (rowbase + t) * 16;
#pragma unroll
            for (int n = 0; n < 16; n++) h[n] = fmaf(h[n], rp[n], bx * bp[n]);
        }
    } else {
        for (int t = 0; t < 32; t++) {
            const size_t ro = (rowbase + t) * 2048 + d;
            const float dtv = (float)dt[ro];
            const float xv  = (float)xs[ro];
            s += dtv;
            const float bx = dtv * xv;
            const float* bp = Bm + (rowbase + t) * 16;
#pragma unroll
            for (int n = 0; n < 16; n++) {
                const float an = -__expf(A_log[(size_t)d * 16 + n]);
                h[n] = fmaf(h[n], __expf(dtv * an), bx * bp[n]);
            }
        }
    }
    const size_t sb = (size_t)bi * 256 + tid;
    sdt_o[sb] = s;
    bf16x8 h0, h1;
#pragma unroll
    for (int n = 0; n < 8; n++) { h0[n] = (bf16_t)h[n]; h1[n] = (bf16_t)h[n + 8]; }
    *(bf16x8*)(Hsum + sb * 16)     = h0;
    *(bf16x8*)(Hsum + sb * 16 + 8) = h1;
}

__global__ __launch_bounds__(256)
void scan2(const float* __restrict__ sdt, bf16_t* __restrict__ Hsum,
           const float* __restrict__ A_log)
{
    const int tid = threadIdx.x;
    const int bb  = blockIdx.x;
    const int d   = (bb & 7) * 256 + tid;
    float a1; const bool fast = fast_check(A_log, d, a1);

    float h[16] = {};
    for (int c = 0; c < 64; c++) {
        const size_t sb = ((size_t)(bb * 64 + c) * 256 + tid);
        const float s = sdt[sb];
        bf16x8 hs0 = *(const bf16x8*)(Hsum + sb * 16);
        bf16x8 hs1 = *(const bf16x8*)(Hsum + sb * 16 + 8);
        bf16x8 o0, o1;
#pragma unroll
        for (int n = 0; n < 8; n++) { o0[n] = (bf16_t)h[n]; o1[n] = (bf16_t)h[n + 8]; }
        *(bf16x8*)(Hsum + sb * 16)     = o0;
        *(bf16x8*)(Hsum + sb * 16 + 8) = o1;
        if (fast) {
            const float r = __expf(s * a1);
            float rp[16]; rp[0] = r;
#pragma unroll
            for (int n = 1; n < 16; n++) rp[n] = rp[n - 1] * r;
#pragma unroll
            for (int n = 0; n < 16; n++) {
                const float hsv = (n < 8) ? (float)hs0[n] : (float)hs1[n - 8];
                h[n] = fmaf(h[n], rp[n], hsv);
            }
        } else {
#pragma unroll
            for (int n = 0; n < 16; n++) {
                const float an = -__expf(A_log[(size_t)d * 16 + n]);
                const float hsv = (n < 8) ? (float)hs0[n] : (float)hs1[n - 8];
                h[n] = fmaf(h[n], __expf(s * an), hsv);
            }
        }
    }
}

__global__ __launch_bounds__(256)
void scan3(const bf16_t* __restrict__ dt, const bf16_t* __restrict__ xs,
           bf16_t* __restrict__ zy,
           const float* __restrict__ Bm, const float* __restrict__ Cm,
           const float* __restrict__ A_log, const float* __restrict__ Dv,
           const bf16_t* __restrict__ Hseed)
{
    const int tid = threadIdx.x;
    const int bi  = blockIdx.x;
    const int c   = bi & 63;
    const int bb  = bi >> 6;
    const int b   = bb >> 3;
    const int d   = (bb & 7) * 256 + tid;
    float a1; const bool fast = fast_check(A_log, d, a1);
    const float Dd = Dv[d];

    const size_t sb = (size_t)bi * 256 + tid;
    const bf16x8 hs0 = *(const bf16x8*)(Hseed + sb * 16);
    const bf16x8 hs1 = *(const bf16x8*)(Hseed + sb * 16 + 8);
    float h[16];
#pragma unroll
    for (int n = 0; n < 8; n++) { h[n] = (float)hs0[n]; h[n + 8] = (float)hs1[n]; }

    const size_t rowbase = (size_t)b * 2048 + c * 32;

    if (fast) {
#pragma unroll 2
        for (int t = 0; t < 32; t++) {
            const size_t ro = (rowbase + t) * 2048 + d;
            const float dtv = (float)dt[ro];
            const float xv  = (float)xs[ro];
            const float zv  = (float)zy[ro];
            const float r = __expf(dtv * a1);
            float rp[16]; rp[0] = r;
#pragma unroll
            for (int n = 1; n < 16; n++) rp[n] = rp[n - 1] * r;
            const float bx = dtv * xv;
            const float* bp = Bm + (rowbase + t) * 16;
            const float* cp = Cm + (rowbase + t) * 16;
            float y0 = 0.f, y1 = 0.f;
#pragma unroll
            for (int n = 0; n < 16; n += 2) {
                h[n]     = fmaf(h[n],     rp[n],     bx * bp[n]);
                h[n + 1] = fmaf(h[n + 1], rp[n + 1], bx * bp[n + 1]);
                y0 = fmaf(h[n],     cp[n],     y0);
                y1 = fmaf(h[n + 1], cp[n + 1], y1);
            }
            const float yv = (y0 + y1) + xv * Dd;
            const float g  = zv / (1.f + __expf(-zv));
            zy[ro] = (bf16_t)(yv * g);
        }
    } else {
        for (int t = 0; t < 32; t++) {
            const size_t ro = (rowbase + t) * 2048 + d;
            const float dtv = (float)dt[ro];
            const float xv  = (float)xs[ro];
            const float zv  = (float)zy[ro];
            const float bx = dtv * xv;
            const float* bp = Bm + (rowbase + t) * 16;
            const float* cp = Cm + (rowbase + t) * 16;
            float y = 0.f;
#pragma unroll
            for (int n = 0; n < 16; n++) {
                const float an = -__expf(A_log[(size_t)d * 16 + n]);
                h[n] = fmaf(h[n], __expf(dtv * an), bx * bp[n]);
                y = fmaf(h[n], cp[n], y);
            }
            const float yv = y + xv * Dd;
            const float g  = zv / (1.f + __expf(-zv));
            zy[ro] = (bf16_t)(yv * g);
        }
    }
}

// ---------------------------------------------------------------------------
extern "C" void kernel_launch(void* const* d_in, const int* in_sizes, int n_in,
                              void* d_out, int out_size, void* d_ws, size_t ws_size,
                              hipStream_t stream)
{
    const float* x     = (const float*)d_in[0];  // [2,2048,1024]
    const float* W_in  = (const float*)d_in[1];  // [4096,1024]
    const float* convw = (const float*)d_in[2];  // [2048,1,4]
    const float* convb = (const float*)d_in[3];  // [2048]
    const float* W_xp  = (const float*)d_in[4];  // [96,2048]
    const float* W_dt  = (const float*)d_in[5];  // [2048,64]
    const float* b_dt  = (const float*)d_in[6];  // [2048]
    const float* A_log = (const float*)d_in[7];  // [2048,16]
    const float* Dv    = (const float*)d_in[8];  // [2048]
    const float* W_out = (const float*)d_in[9];  // [1024,2048]

    char* ws = (char*)d_ws;
    bf16_t* bufP   = (bf16_t*)(ws + 0);          // xs_pre -> later dt       (16.78 MB)
    bf16_t* bufZ   = (bf16_t*)(ws + 16777216);   // z -> yg in-place         (16.78 MB)
    bf16_t* bufX   = (bf16_t*)(ws + 33554432);   // xs (conv out), stage>=2  (16.78 MB)
    bf16_t* W_in_b = (bf16_t*)(ws + 33554432);   // ALIAS: dead before bufX written
    bf16_t* dtr    = (bf16_t*)(ws + 50331648);   // [4096,64]
    float*  Bm     = (float*)(ws + 50855936);    // [4096,16]
    float*  Cm     = (float*)(ws + 51118080);    // [4096,16]
    float*  sdt    = (float*)(ws + 51380224);    // [1024*256]               (1.05 MB)
    bf16_t* Hsum   = (bf16_t*)(ws + 52428800);   // [1024*256*16], stage 5   (8.39 MB)
    bf16_t* x_b    = (bf16_t*)(ws + 52428800);   // ALIAS: dead before Hsum written
    bf16_t* W_out_b= (bf16_t*)(ws + 60817408);   // [1024,2048]              (4.19 MB)
    bf16_t* W_xp_b = (bf16_t*)(ws + 65011712);   // [96,2048]                (0.39 MB)
    bf16_t* W_dt_b = (bf16_t*)(ws + 65404928);   // [2048,64]                (0.26 MB)
    // split-K partials (alive only during out_proj; bufP/bufX dead by then):
    float*  P0     = (float*)(ws + 0);           // aliases bufP (dead)
    float*  P1     = (float*)(ws + 33554432);    // aliases bufX (dead)
    float*  P2     = (float*)(ws + 65667072);    // fresh tail (16.78 MB)
    float*  P3     = (float*)(ws + 82444288);    // fresh tail (16.78 MB) end 99.2 MB
    const bool sk4 = (ws_size >= 99221504ull);   // deterministic per-session

    // 0) cast all GEMM operands fp32 -> bf16 (one fused kernel)
    cast5<<<dim3(4096 + 4096 + 2048 + 192 + 128), dim3(256), 0, stream>>>(
        x, x_b, 4096, W_in, W_in_b, 4096, W_out, W_out_b, 2048,
        W_xp, W_xp_b, 192, W_dt, W_dt_b);

    // 1) in_proj: xz = x @ W_in^T -> bufP (xs_pre), bufZ (z)
    gemm_bt<1, 1><<<dim3(32, 32), dim3(256), 0, stream>>>(
        x_b, W_in_b, 4096, 4096, 1024, (void*)bufP, (void*)bufZ, nullptr,
        nullptr, nullptr, nullptr, nullptr);

    // 2) conv + bias + silu -> bufX
    conv_silu<<<dim3(32768), dim3(256), 0, stream>>>(bufP, convw, convb, bufX);

    // 3) x_proj -> dtr, Bm, Cm
    xproj_kernel<<<dim3(256), dim3(64), 0, stream>>>(bufX, W_xp_b, dtr, Bm, Cm);

    // 4) dt_proj + softplus -> bufP (dt)
    gemm_bt<2, 1><<<dim3(16, 32), dim3(256), 0, stream>>>(
        dtr, W_dt_b, 4096, 2048, 64, (void*)bufP, nullptr, b_dt,
        nullptr, nullptr, nullptr, nullptr);

    // 5) register-state chunked scan + skip + gate -> bufZ in place
    scan1<<<dim3(1024), dim3(256), 0, stream>>>(bufP, bufX, Bm, A_log, sdt, Hsum);
    scan2<<<dim3(16),   dim3(256), 0, stream>>>(sdt, Hsum, A_log);
    scan3<<<dim3(1024), dim3(256), 0, stream>>>(bufP, bufX, bufZ, Bm, Cm, A_log, Dv, Hsum);

    // 6) out_proj, split-K for occupancy (4 blocks/CU if ws allows, else 2)
    if (sk4) {
        gemm_bt<3, 4><<<dim3(8, 32, 4), dim3(256), 0, stream>>>(
            bufZ, W_out_b, 4096, 1024, 2048, nullptr, nullptr, nullptr,
            P0, P1, P2, P3);
        reduce_k<<<dim3(4096), dim3(256), 0, stream>>>(
            (float*)d_out, P0, P1, P2, P3, 4);
    } else {
        gemm_bt<3, 2><<<dim3(8, 32, 2), dim3(256), 0, stream>>>(
            bufZ, W_out_b, 4096, 1024, 2048, nullptr, nullptr, nullptr,
            P0, P1, nullptr, nullptr);
        reduce_k<<<dim3(4096), dim3(256), 0, stream>>>(
            (float*)d_out, P0, P1, nullptr, nullptr, 2);
    }
}

// Round 10
// 334.005 us; speedup vs baseline: 2.3233x; 1.0145x over previous
//
#include <hip/hip_runtime.h>
#include <cstdint>
#include <cstddef>

typedef __bf16 bf16_t;
typedef bf16_t bf16x4 __attribute__((ext_vector_type(4)));
typedef bf16_t bf16x8 __attribute__((ext_vector_type(8)));
typedef float f32x4 __attribute__((ext_vector_type(4)));

// async global->LDS, 16B per lane; LDS dest = wave-uniform base + lane*16
static __device__ __forceinline__ void glds16(const void* g, void* l) {
    __builtin_amdgcn_global_load_lds((const __attribute__((address_space(1))) void*)g,
                                     (__attribute__((address_space(3))) void*)l,
                                     16, 0, 0);
}

// ---------------------------------------------------------------------------
// One-shot fp32 -> bf16 cast of the five GEMM operands. 1024 elts / block.
// ---------------------------------------------------------------------------
__global__ __launch_bounds__(256)
void cast5(const float* __restrict__ s0, bf16_t* __restrict__ d0, int n0,
           const float* __restrict__ s1, bf16_t* __restrict__ d1, int n1,
           const float* __restrict__ s2, bf16_t* __restrict__ d2, int n2,
           const float* __restrict__ s3, bf16_t* __restrict__ d3, int n3,
           const float* __restrict__ s4, bf16_t* __restrict__ d4)
{
    int bb = blockIdx.x;
    const float* s; bf16_t* d;
    if (bb < n0)              { s = s0; d = d0; }
    else if ((bb -= n0) < n1) { s = s1; d = d1; }
    else if ((bb -= n1) < n2) { s = s2; d = d2; }
    else if ((bb -= n2) < n3) { s = s3; d = d3; }
    else                      { bb -= n3; s = s4; d = d4; }
    const size_t base = (size_t)bb * 1024 + threadIdx.x * 4;
    const f32x4 v = *(const f32x4*)(s + base);
    bf16x4 o;
    o[0] = (bf16_t)v[0]; o[1] = (bf16_t)v[1]; o[2] = (bf16_t)v[2]; o[3] = (bf16_t)v[3];
    *(bf16x4*)(d + base) = o;
}

// ---------------------------------------------------------------------------
// GEMM: C[M,N] = A[M,K](bf16) * Bt[N,K](bf16)^T, MFMA 16x16x32, 128x128 tile,
// BK=64 (32 MFMA between barriers; k-halves sequential to cap VGPR), glds16
// async staging. SPLITK via blockIdx.z; EPI 3 stores fp32 partials.
// EPI 0: fp32 -> o0[gr*N+gc]
// EPI 1: gc<2048 -> bf16 o0 (ld 2048) else bf16 o1  [in_proj split xs_pre / z]
// EPI 2: bf16 o0 = softplus(acc + bias_f32[gc])     [dt_proj]
// EPI 3: fp32 partial -> pz[gr*N+gc]                [out_proj split-K]
// Requires K % 64 == 0 (true: 1024, 64, 512-chunks).
// ---------------------------------------------------------------------------
template<int EPI, int SPLITK>
__global__ __launch_bounds__(256)
void gemm_bt(const bf16_t* __restrict__ A, const bf16_t* __restrict__ Bt,
             const int M, const int N, const int K,
             void* __restrict__ o0, void* __restrict__ o1,
             const float* __restrict__ bias,
             float* __restrict__ p0, float* __restrict__ p1,
             float* __restrict__ p2, float* __restrict__ p3)
{
    __shared__ __align__(16) bf16_t As[128 * 64];
    __shared__ __align__(16) bf16_t Bs[128 * 64];

    const int tid  = threadIdx.x;
    const int lane = tid & 63;
    const int wave = tid >> 6;
    const int wm = wave & 1, wn = wave >> 1;
    const int m0 = blockIdx.y * 128, n0 = blockIdx.x * 128;
    const int quad = lane >> 4, l16 = lane & 15;
    const int z   = (SPLITK > 1) ? blockIdx.z : 0;
    const int KC  = K / SPLITK;
    const int kb  = z * KC;

    f32x4 acc[4][4] = {};

    for (int k0 = kb; k0 < kb + KC; k0 += 64) {
        __syncthreads();
#pragma unroll
        for (int j = 0; j < 4; j++) {
            const int u  = wave * 2048 + j * 512;   // wave-uniform LDS elem base
            const int ue = u + lane * 8;            // per-lane element index
            const int row = ue >> 6, col = ue & 63;
            glds16(A  + (size_t)(m0 + row) * K + k0 + col, As + u);
            glds16(Bt + (size_t)(n0 + row) * K + k0 + col, Bs + u);
        }
        __syncthreads();

#pragma unroll
        for (int kk = 0; kk < 2; kk++) {
            bf16x8 afr[4], bfr[4];
#pragma unroll
            for (int mt = 0; mt < 4; mt++)
                afr[mt] = *(const bf16x8*)(As + (wm * 64 + mt * 16 + l16) * 64 + kk * 32 + quad * 8);
#pragma unroll
            for (int nt = 0; nt < 4; nt++)
                bfr[nt] = *(const bf16x8*)(Bs + (wn * 64 + nt * 16 + l16) * 64 + kk * 32 + quad * 8);
#pragma unroll
            for (int mt = 0; mt < 4; mt++)
#pragma unroll
                for (int nt = 0; nt < 4; nt++)
                    acc[mt][nt] = __builtin_amdgcn_mfma_f32_16x16x32_bf16(
                        afr[mt], bfr[nt], acc[mt][nt], 0, 0, 0);
        }
    }

    float* pz = (z == 0) ? p0 : (z == 1) ? p1 : (z == 2) ? p2 : p3;

    // C/D layout (m89-verified): col = lane&15, row = quad*4 + reg
#pragma unroll
    for (int mt = 0; mt < 4; mt++)
#pragma unroll
        for (int nt = 0; nt < 4; nt++)
#pragma unroll
            for (int r = 0; r < 4; r++) {
                const int gr = m0 + wm * 64 + mt * 16 + quad * 4 + r;
                const int gc = n0 + wn * 64 + nt * 16 + l16;
                const float v = acc[mt][nt][r];
                if (EPI == 0) {
                    ((float*)o0)[(size_t)gr * N + gc] = v;
                } else if (EPI == 1) {
                    if (gc < 2048) ((bf16_t*)o0)[(size_t)gr * 2048 + gc] = (bf16_t)v;
                    else           ((bf16_t*)o1)[(size_t)gr * 2048 + (gc - 2048)] = (bf16_t)v;
                } else if (EPI == 2) {
                    const float t  = v + bias[gc];
                    const float sp = (t > 15.f) ? t : __logf(1.f + __expf(t));
                    ((bf16_t*)o0)[(size_t)gr * 2048 + gc] = (bf16_t)sp;
                } else {
                    pz[(size_t)gr * N + gc] = v;
                }
            }
}

// ---------------------------------------------------------------------------
// Split-K reduce: d_out[i] = sum_z partial_z[i]  (fp32, f32x4 vectorized)
// ---------------------------------------------------------------------------
__global__ __launch_bounds__(256)
void reduce_k(float* __restrict__ out, const float* __restrict__ p0,
              const float* __restrict__ p1, const float* __restrict__ p2,
              const float* __restrict__ p3, const int nsplit)
{
    const size_t i = ((size_t)blockIdx.x * 256 + threadIdx.x) * 4;
    f32x4 v = *(const f32x4*)(p0 + i);
    v += *(const f32x4*)(p1 + i);
    if (nsplit == 4) {
        v += *(const f32x4*)(p2 + i);
        v += *(const f32x4*)(p3 + i);
    }
    *(f32x4*)(out + i) = v;
}

// ---------------------------------------------------------------------------
// Causal depthwise conv (k=4, fp32 weights/bias) + SiLU. (unchanged)
// ---------------------------------------------------------------------------
__global__ __launch_bounds__(256)
void conv_silu(const bf16_t* __restrict__ xs_pre, const float* __restrict__ cw,
               const float* __restrict__ cb, bf16_t* __restrict__ xs)
{
    const int idx = blockIdx.x * 256 + threadIdx.x;  // over B*L*2048
    const int d   = idx & 2047;
    const int row = idx >> 11;     // b*L + l
    const int l   = row & 2047;    // L = 2048
    const float w0 = cw[d * 4 + 0], w1 = cw[d * 4 + 1];
    const float w2 = cw[d * 4 + 2], w3 = cw[d * 4 + 3];
    const bf16_t* p = xs_pre + (size_t)row * 2048 + d;
    float acc = cb[d] + w3 * (float)p[0];
    if (l >= 1) acc += w2 * (float)p[-2048];
    if (l >= 2) acc += w1 * (float)p[-4096];
    if (l >= 3) acc += w0 * (float)p[-6144];
    const float s = acc / (1.f + __expf(-acc));
    xs[idx] = (bf16_t)s;
}

// ---------------------------------------------------------------------------
// x_proj: x_dbl[4096,96] = xs[4096,2048](bf16) @ W_xp_b[96,2048](bf16)^T.
// ---------------------------------------------------------------------------
__global__ __launch_bounds__(64)
void xproj_kernel(const bf16_t* __restrict__ A, const bf16_t* __restrict__ Bt,
                  bf16_t* __restrict__ dtr, float* __restrict__ Bm, float* __restrict__ Cm)
{
    const int lane = threadIdx.x;
    const int m0 = blockIdx.x * 16;
    const int l16 = lane & 15, quad = lane >> 4;
    f32x4 acc[6] = {};

    const bf16_t* ap = A + (size_t)(m0 + l16) * 2048 + quad * 8;
    for (int k0 = 0; k0 < 2048; k0 += 32) {
        const bf16x8 afr = *(const bf16x8*)(ap + k0);
#pragma unroll
        for (int t = 0; t < 6; t++) {
            const bf16x8 bfr = *(const bf16x8*)(Bt + (size_t)(t * 16 + l16) * 2048 + k0 + quad * 8);
            acc[t] = __builtin_amdgcn_mfma_f32_16x16x32_bf16(afr, bfr, acc[t], 0, 0, 0);
        }
    }
#pragma unroll
    for (int t = 0; t < 6; t++)
#pragma unroll
        for (int r = 0; r < 4; r++) {
            const int gr = m0 + quad * 4 + r;
            const int gc = t * 16 + l16;
            const float v = acc[t][r];
            if (gc < 64)      dtr[(size_t)gr * 64 + gc] = (bf16_t)v;
            else if (gc < 80) Bm[(size_t)gr * 16 + (gc - 64)] = v;
            else              Cm[(size_t)gr * 16 + (gc - 80)] = v;
        }
}

// ---------------------------------------------------------------------------
// Register-state chunked scan (unchanged from round 7).
// ---------------------------------------------------------------------------
static __device__ __forceinline__ bool fast_check(const float* A_log, int d, float& a1) {
    a1 = -__expf(A_log[(size_t)d * 16]);
    bool ok = true;
#pragma unroll
    for (int n = 1; n < 16; n++) {
        const float an = -__expf(A_log[(size_t)d * 16 + n]);
        const float pn = (float)(n + 1) * a1;
        ok = ok && (fabsf(an - pn) <= 1e-3f * fabsf(pn) + 1e-6f);
    }
    return ok;
}

__global__ __launch_bounds__(256)
void scan1(const bf16_t* __restrict__ dt, const bf16_t* __restrict__ xs,
           const float* __restrict__ Bm, const float* __restrict__ A_log,
           float* __restrict__ sdt_o, bf16_t* __restrict__ Hsum)
{
    const int tid = threadIdx.x;
    const int bi  = blockIdx.x;
    const int c   = bi & 63;
    const int bb  = bi >> 6;
    const int b   = bb >> 3;
    const int d   = (bb & 7) * 256 + tid;
    float a1; const bool fast = fast_check(A_log, d, a1);

    float h[16] = {};
    float s = 0.f;
    const size_t rowbase = (size_t)b * 2048 + c * 32;

    if (fast) {
#pragma unroll 4
        for (int t = 0; t < 32; t++) {
            const size_t ro = (rowbase + t) * 2048 + d;
            const float dtv = (float)dt[ro];
            const float xv  = (float)xs[ro];
            s += dtv;
            const float r = __expf(dtv * a1);
            float rp[16]; rp[0] = r;
#pragma unroll
            for (int n = 1; n < 16; n++) rp[n] = rp[n - 1] * r;
            const float bx = dtv * xv;
            const float* bp = Bm + (rowbase + t) * 16;
#pragma unroll
            for (int n = 0; n < 16; n++) h[n] = fmaf(h[n], rp[n], bx * bp[n]);
        }
    } else {
        for (int t = 0; t < 32; t++) {
            const size_t ro = (rowbase + t) * 2048 + d;
            const float dtv = (float)dt[ro];
            const float xv  = (float)xs[ro];
            s += dtv;
            const float bx = dtv * xv;
            const float* bp = Bm + (rowbase + t) * 16;
#pragma unroll
            for (int n = 0; n < 16; n++) {
                const float an = -__expf(A_log[(size_t)d * 16 + n]);
                h[n] = fmaf(h[n], __expf(dtv * an), bx * bp[n]);
            }
        }
    }
    const size_t sb = (size_t)bi * 256 + tid;
    sdt_o[sb] = s;
    bf16x8 h0, h1;
#pragma unroll
    for (int n = 0; n < 8; n++) { h0[n] = (bf16_t)h[n]; h1[n] = (bf16_t)h[n + 8]; }
    *(bf16x8*)(Hsum + sb * 16)     = h0;
    *(bf16x8*)(Hsum + sb * 16 + 8) = h1;
}

__global__ __launch_bounds__(256)
void scan2(const float* __restrict__ sdt, bf16_t* __restrict__ Hsum,
           const float* __restrict__ A_log)
{
    const int tid = threadIdx.x;
    const int bb  = blockIdx.x;
    const int d   = (bb & 7) * 256 + tid;
    float a1; const bool fast = fast_check(A_log, d, a1);

    float h[16] = {};
    for (int c = 0; c < 64; c++) {
        const size_t sb = ((size_t)(bb * 64 + c) * 256 + tid);
        const float s = sdt[sb];
        bf16x8 hs0 = *(const bf16x8*)(Hsum + sb * 16);
        bf16x8 hs1 = *(const bf16x8*)(Hsum + sb * 16 + 8);
        bf16x8 o0, o1;
#pragma unroll
        for (int n = 0; n < 8; n++) { o0[n] = (bf16_t)h[n]; o1[n] = (bf16_t)h[n + 8]; }
        *(bf16x8*)(Hsum + sb * 16)     = o0;
        *(bf16x8*)(Hsum + sb * 16 + 8) = o1;
        if (fast) {
            const float r = __expf(s * a1);
            float rp[16]; rp[0] = r;
#pragma unroll
            for (int n = 1; n < 16; n++) rp[n] = rp[n - 1] * r;
#pragma unroll
            for (int n = 0; n < 16; n++) {
                const float hsv = (n < 8) ? (float)hs0[n] : (float)hs1[n - 8];
                h[n] = fmaf(h[n], rp[n], hsv);
            }
        } else {
#pragma unroll
            for (int n = 0; n < 16; n++) {
                const float an = -__expf(A_log[(size_t)d * 16 + n]);
                const float hsv = (n < 8) ? (float)hs0[n] : (float)hs1[n - 8];
                h[n] = fmaf(h[n], __expf(s * an), hsv);
            }
        }
    }
}

__global__ __launch_bounds__(256)
void scan3(const bf16_t* __restrict__ dt, const bf16_t* __restrict__ xs,
           bf16_t* __restrict__ zy,
           const float* __restrict__ Bm, const float* __restrict__ Cm,
           const float* __restrict__ A_log, const float* __restrict__ Dv,
           const bf16_t* __restrict__ Hseed)
{
    const int tid = threadIdx.x;
    const int bi  = blockIdx.x;
    const int c   = bi & 63;
    const int bb  = bi >> 6;
    const int b   = bb >> 3;
    const int d   = (bb & 7) * 256 + tid;
    float a1; const bool fast = fast_check(A_log, d, a1);
    const float Dd = Dv[d];

    const size_t sb = (size_t)bi * 256 + tid;
    const bf16x8 hs0 = *(const bf16x8*)(Hseed + sb * 16);
    const bf16x8 hs1 = *(const bf16x8*)(Hseed + sb * 16 + 8);
    float h[16];
#pragma unroll
    for (int n = 0; n < 8; n++) { h[n] = (float)hs0[n]; h[n + 8] = (float)hs1[n]; }

    const size_t rowbase = (size_t)b * 2048 + c * 32;

    if (fast) {
#pragma unroll 2
        for (int t = 0; t < 32; t++) {
            const size_t ro = (rowbase + t) * 2048 + d;
            const float dtv = (float)dt[ro];
            const float xv  = (float)xs[ro];
            const float zv  = (float)zy[ro];
            const float r = __expf(dtv * a1);
            float rp[16]; rp[0] = r;
#pragma unroll
            for (int n = 1; n < 16; n++) rp[n] = rp[n - 1] * r;
            const float bx = dtv * xv;
            const float* bp = Bm + (rowbase + t) * 16;
            const float* cp = Cm + (rowbase + t) * 16;
            float y0 = 0.f, y1 = 0.f;
#pragma unroll
            for (int n = 0; n < 16; n += 2) {
                h[n]     = fmaf(h[n],     rp[n],     bx * bp[n]);
                h[n + 1] = fmaf(h[n + 1], rp[n + 1], bx * bp[n + 1]);
                y0 = fmaf(h[n],     cp[n],     y0);
                y1 = fmaf(h[n + 1], cp[n + 1], y1);
            }
            const float yv = (y0 + y1) + xv * Dd;
            const float g  = zv / (1.f + __expf(-zv));
            zy[ro] = (bf16_t)(yv * g);
        }
    } else {
        for (int t = 0; t < 32; t++) {
            const size_t ro = (rowbase + t) * 2048 + d;
            const float dtv = (float)dt[ro];
            const float xv  = (float)xs[ro];
            const float zv  = (float)zy[ro];
            const float bx = dtv * xv;
            const float* bp = Bm + (rowbase + t) * 16;
            const float* cp = Cm + (rowbase + t) * 16;
            float y = 0.f;
#pragma unroll
            for (int n = 0; n < 16; n++) {
                const float an = -__expf(A_log[(size_t)d * 16 + n]);
                h[n] = fmaf(h[n], __expf(dtv * an), bx * bp[n]);
                y = fmaf(h[n], cp[n], y);
            }
            const float yv = y + xv * Dd;
            const float g  = zv / (1.f + __expf(-zv));
            zy[ro] = (bf16_t)(yv * g);
        }
    }
}

// ---------------------------------------------------------------------------
extern "C" void kernel_launch(void* const* d_in, const int* in_sizes, int n_in,
                              void* d_out, int out_size, void* d_ws, size_t ws_size,
                              hipStream_t stream)
{
    const float* x     = (const float*)d_in[0];  // [2,2048,1024]
    const float* W_in  = (const float*)d_in[1];  // [4096,1024]
    const float* convw = (const float*)d_in[2];  // [2048,1,4]
    const float* convb = (const float*)d_in[3];  // [2048]
    const float* W_xp  = (const float*)d_in[4];  // [96,2048]
    const float* W_dt  = (const float*)d_in[5];  // [2048,64]
    const float* b_dt  = (const float*)d_in[6];  // [2048]
    const float* A_log = (const float*)d_in[7];  // [2048,16]
    const float* Dv    = (const float*)d_in[8];  // [2048]
    const float* W_out = (const float*)d_in[9];  // [1024,2048]

    char* ws = (char*)d_ws;
    bf16_t* bufP   = (bf16_t*)(ws + 0);          // xs_pre -> later dt       (16.78 MB)
    bf16_t* bufZ   = (bf16_t*)(ws + 16777216);   // z -> yg in-place         (16.78 MB)
    bf16_t* bufX   = (bf16_t*)(ws + 33554432);   // xs (conv out), stage>=2  (16.78 MB)
    bf16_t* W_in_b = (bf16_t*)(ws + 33554432);   // ALIAS: dead before bufX written
    bf16_t* dtr    = (bf16_t*)(ws + 50331648);   // [4096,64]
    float*  Bm     = (float*)(ws + 50855936);    // [4096,16]
    float*  Cm     = (float*)(ws + 51118080);    // [4096,16]
    float*  sdt    = (float*)(ws + 51380224);    // [1024*256]               (1.05 MB)
    bf16_t* Hsum   = (bf16_t*)(ws + 52428800);   // [1024*256*16], stage 5   (8.39 MB)
    bf16_t* x_b    = (bf16_t*)(ws + 52428800);   // ALIAS: dead before Hsum written
    bf16_t* W_out_b= (bf16_t*)(ws + 60817408);   // [1024,2048]              (4.19 MB)
    bf16_t* W_xp_b = (bf16_t*)(ws + 65011712);   // [96,2048]                (0.39 MB)
    bf16_t* W_dt_b = (bf16_t*)(ws + 65404928);   // [2048,64]                (0.26 MB)
    // split-K partials (alive only during out_proj; bufP/bufX dead by then):
    float*  P0     = (float*)(ws + 0);           // aliases bufP (dead)
    float*  P1     = (float*)(ws + 33554432);    // aliases bufX (dead)
    float*  P2     = (float*)(ws + 65667072);    // fresh tail (16.78 MB)
    float*  P3     = (float*)(ws + 82444288);    // fresh tail (16.78 MB) end 99.2 MB
    const bool sk4 = (ws_size >= 99221504ull);   // deterministic per-session

    // 0) cast all GEMM operands fp32 -> bf16 (one fused kernel)
    cast5<<<dim3(4096 + 4096 + 2048 + 192 + 128), dim3(256), 0, stream>>>(
        x, x_b, 4096, W_in, W_in_b, 4096, W_out, W_out_b, 2048,
        W_xp, W_xp_b, 192, W_dt, W_dt_b);

    // 1) in_proj: xz = x @ W_in^T -> bufP (xs_pre), bufZ (z)
    gemm_bt<1, 1><<<dim3(32, 32), dim3(256), 0, stream>>>(
        x_b, W_in_b, 4096, 4096, 1024, (void*)bufP, (void*)bufZ, nullptr,
        nullptr, nullptr, nullptr, nullptr);

    // 2) conv + bias + silu -> bufX
    conv_silu<<<dim3(32768), dim3(256), 0, stream>>>(bufP, convw, convb, bufX);

    // 3) x_proj -> dtr, Bm, Cm
    xproj_kernel<<<dim3(256), dim3(64), 0, stream>>>(bufX, W_xp_b, dtr, Bm, Cm);

    // 4) dt_proj + softplus -> bufP (dt)  (K=64 -> single BK=64 iteration)
    gemm_bt<2, 1><<<dim3(16, 32), dim3(256), 0, stream>>>(
        dtr, W_dt_b, 4096, 2048, 64, (void*)bufP, nullptr, b_dt,
        nullptr, nullptr, nullptr, nullptr);

    // 5) register-state chunked scan + skip + gate -> bufZ in place
    scan1<<<dim3(1024), dim3(256), 0, stream>>>(bufP, bufX, Bm, A_log, sdt, Hsum);
    scan2<<<dim3(16),   dim3(256), 0, stream>>>(sdt, Hsum, A_log);
    scan3<<<dim3(1024), dim3(256), 0, stream>>>(bufP, bufX, bufZ, Bm, Cm, A_log, Dv, Hsum);

    // 6) out_proj, split-K for occupancy (4 blocks/CU if ws allows, else 2)
    if (sk4) {
        gemm_bt<3, 4><<<dim3(8, 32, 4), dim3(256), 0, stream>>>(
            bufZ, W_out_b, 4096, 1024, 2048, nullptr, nullptr, nullptr,
            P0, P1, P2, P3);
        reduce_k<<<dim3(4096), dim3(256), 0, stream>>>(
            (float*)d_out, P0, P1, P2, P3, 4);
    } else {
        gemm_bt<3, 2><<<dim3(8, 32, 2), dim3(256), 0, stream>>>(
            bufZ, W_out_b, 4096, 1024, 2048, nullptr, nullptr, nullptr,
            P0, P1, nullptr, nullptr);
        reduce_k<<<dim3(4096), dim3(256), 0, stream>>>(
            (float*)d_out, P0, P1, nullptr, nullptr, 2);
    }
}